// Round 15
// baseline (733.114 us; speedup 1.0000x reference)
//
#include <hip/hip_runtime.h>
#include <math.h>

#define H 128
#define NHEADS 3
#define BGR 16
#define N0C 2048
#define N1C 1024
#define N2C 512
#define KNN 10
#define EPSV 1e-5f

typedef unsigned short ushortT;
typedef __attribute__((ext_vector_type(8))) short short8;
typedef __attribute__((ext_vector_type(4))) short s16x4;
typedef __attribute__((ext_vector_type(4))) float f32x4;
typedef __attribute__((ext_vector_type(2))) float f32x2;

static __device__ __forceinline__ unsigned short f2bf(float f) {
    unsigned u = __float_as_uint(f);
    unsigned r = (u + 0x7FFF + ((u >> 16) & 1)) >> 16;
    return (unsigned short)r;
}
static __device__ __forceinline__ float bf2f(unsigned short s) {
    return __uint_as_float(((unsigned)s) << 16);
}

// ---------------- decode edge -> (src,dst) from knn table ----------------
static __device__ __forceinline__ int decode_src(int e, int BNK, const int* __restrict__ knn) {
    if (e < BNK) return knn[e];
    int f = e - BNK;
    if (f < BNK) return f / KNN;
    return f - BNK;
}
static __device__ __forceinline__ int decode_dst(int e, int BNK, const int* __restrict__ knn) {
    if (e < BNK) return e / KNN;
    int f = e - BNK;
    if (f < BNK) return knn[f];
    return f - BNK;
}

// ---------------- batchnorm ----------------
__global__ void colstats_k(const float* __restrict__ xin, int rows, float* __restrict__ part) {
    int c = threadIdx.x & 127, rr = threadIdx.x >> 7;
    float s = 0.f, q = 0.f;
    for (int r = blockIdx.x * 2 + rr; r < rows; r += 256) {
        float v = xin[(size_t)r * H + c];
        s += v; q += v * v;
    }
    __shared__ float ls[256], lq[256];
    ls[threadIdx.x] = s; lq[threadIdx.x] = q;
    __syncthreads();
    if (rr == 0) {
        part[blockIdx.x * 256 + c]       = s + ls[threadIdx.x + 128];
        part[blockIdx.x * 256 + 128 + c] = q + lq[threadIdx.x + 128];
    }
}
__global__ void colreduce_k(const float* __restrict__ part, float* __restrict__ stats) {
    int t = threadIdx.x; // 256
    float s = 0.f;
    for (int p = 0; p < 128; p++) s += part[p * 256 + t];
    stats[t] = s;
}
__global__ void bn_apply_k(const float* __restrict__ xin, float* __restrict__ xout,
                           ushortT* __restrict__ bfout,
                           const float* __restrict__ stats, const float* __restrict__ g,
                           const float* __restrict__ b, int rows) {
    int idx = blockIdx.x * 256 + threadIdx.x;
    if (idx >= rows * H) return;
    int c = idx & 127;
    float mean = stats[c] / rows;
    float var = stats[128 + c] / rows - mean * mean;
    float v = (xin[idx] - mean) * rsqrtf(var + EPSV) * g[c] + b[c];
    xout[idx] = v;
    if (bfout) bfout[idx] = f2bf(v);
}

// ---------------- matvec (dot-128 per row) ----------------
__global__ void matvec_k(const float* __restrict__ hsrc, const float* __restrict__ w,
                         const float* __restrict__ bias, float* __restrict__ out, int rows) {
    int wv = blockIdx.x * 4 + (threadIdx.x >> 6);
    int lane = threadIdx.x & 63;
    if (wv >= rows) return;
    float acc = hsrc[(size_t)wv * H + lane] * w[lane] + hsrc[(size_t)wv * H + 64 + lane] * w[64 + lane];
    for (int off = 32; off; off >>= 1) acc += __shfl_xor(acc, off);
    if (lane == 0) out[wv] = acc + (bias ? bias[0] : 0.f);
}

// ---------------- top-k pool: rank raw logits, 4 threads per i ----------------
__global__ void pool_rank_k(const float* __restrict__ logit, int n, int keep,
                            int* __restrict__ perm, float* __restrict__ vals) {
    __shared__ float s[2048];
    __shared__ float red[256];
    int groups = n >> 6;
    int b = blockIdx.x / groups, ch = blockIdx.x % groups;
    int t = threadIdx.x; // 256
    const float* L = logit + b * n;
    float mx = -1e30f;
    for (int i = t; i < n; i += 256) { float v = L[i]; s[i] = v; mx = fmaxf(mx, v); }
    red[t] = mx; __syncthreads();
    for (int st = 128; st; st >>= 1) { if (t < st) red[t] = fmaxf(red[t], red[t + st]); __syncthreads(); }
    mx = red[0]; __syncthreads();
    float sm = 0.f;
    for (int i = t; i < n; i += 256) sm += __expf(s[i] - mx);
    red[t] = sm; __syncthreads();
    for (int st = 128; st; st >>= 1) { if (t < st) red[t] += red[t + st]; __syncthreads(); }
    float inv = 1.f / red[0];
    __syncthreads();
    int il = t >> 2, q = t & 3;
    int i = ch * 64 + il;
    float si = s[i];
    int cnt = 0;
    const float4* s4 = (const float4*)s;
    int K4 = n >> 4;
    #pragma unroll 4
    for (int kk = 0; kk < K4; kk++) {
        int jj = kk * 4 + q;
        float4 v = s4[jj];
        int jb = jj * 4;
        cnt += (v.x > si) || (v.x == si && (jb + 0) < i);
        cnt += (v.y > si) || (v.y == si && (jb + 1) < i);
        cnt += (v.z > si) || (v.z == si && (jb + 2) < i);
        cnt += (v.w > si) || (v.w == si && (jb + 3) < i);
    }
    cnt += __shfl_xor(cnt, 1);
    cnt += __shfl_xor(cnt, 2);
    if (q == 0 && cnt < keep) { perm[b * keep + cnt] = b * n + i; vals[b * keep + cnt] = __expf(si - mx) * inv; }
}
__global__ void pool_gather_k(const float* __restrict__ hsrc, const float* __restrict__ possrc,
                              const int* __restrict__ perm, const float* __restrict__ vals,
                              float* __restrict__ hd, ushortT* __restrict__ bfout,
                              float* __restrict__ posd, int rows) {
    int idx = blockIdx.x * 256 + threadIdx.x;
    if (idx >= rows * H) return;
    int r = idx >> 7, c = idx & 127;
    int p = perm[r];
    float v = hsrc[(size_t)p * H + c] * vals[r];
    hd[idx] = v;
    bfout[idx] = f2bf(v);
    if (c < 3) posd[r * 3 + c] = possrc[p * 3 + c];
}

// ---------------- attention readout: softmax fused into weighted column sum ----------------
__global__ void att_partial_k(const float* __restrict__ hsrc, const float* __restrict__ plog,
                              int n, float* __restrict__ part) {
    __shared__ float s[1024];
    __shared__ float red[256];
    int chunks = n >> 6;
    int b = blockIdx.x / chunks, ch = blockIdx.x % chunks;
    int t = threadIdx.x;
    const float* L = plog + b * n;
    float mx = -1e30f;
    for (int i = t; i < n; i += 256) { float v = L[i]; s[i] = v; mx = fmaxf(mx, v); }
    red[t] = mx; __syncthreads();
    for (int st = 128; st; st >>= 1) { if (t < st) red[t] = fmaxf(red[t], red[t + st]); __syncthreads(); }
    mx = red[0]; __syncthreads();
    float sm = 0.f;
    for (int i = t; i < n; i += 256) sm += __expf(s[i] - mx);
    red[t] = sm; __syncthreads();
    for (int st = 128; st; st >>= 1) { if (t < st) red[t] += red[t + st]; __syncthreads(); }
    float inv = 1.f / red[0];
    __syncthreads();
    int c = t & 127, rg = t >> 7;
    int r0 = ch * 64;
    float acc = 0.f;
    for (int i = rg; i < 64; i += 2) {
        int r = r0 + i;
        acc += __expf(s[r] - mx) * inv * hsrc[((size_t)b * n + r) * H + c];
    }
    red[t] = acc; __syncthreads();
    if (rg == 0) part[((size_t)b * chunks + ch) * H + c] = red[c] + red[128 + c];
}
// fused chunk-reduce + [1,128]@[128,256] readout GEMM
__global__ void ro_gemm_k(const float* __restrict__ part, int chunks,
                          const float* __restrict__ w, const float* __restrict__ bias,
                          float* __restrict__ catp, int coff) {
    int b = blockIdx.x, d = threadIdx.x; // 256
    __shared__ float hb[128];
    if (d < 128) {
        float s2 = 0.f;
        for (int ch = 0; ch < chunks; ch++) s2 += part[((size_t)b * chunks + ch) * H + d];
        hb[d] = s2;
    }
    __syncthreads();
    float acc = bias[d];
    for (int c = 0; c < 128; c++) acc += hb[c] * w[c * 256 + d];
    catp[b * 768 + coff + d] = acc;
}

// ---------------- kNN (k=10, includes self) — register-resident, 4-chain argmin ----------------
__global__ void knn_k(const float* __restrict__ pos, int n, int* __restrict__ knn,
                      int* __restrict__ deg) {
    int wv = blockIdx.x * 4 + (threadIdx.x >> 6);
    int lane = threadIdx.x & 63;
    int b = wv / n;
    const float* pb = pos + (size_t)b * n * 3;
    float px = pos[(size_t)wv * 3], py = pos[(size_t)wv * 3 + 1], pz = pos[(size_t)wv * 3 + 2];
    int T = n >> 6;
    float d2v[16];
    #pragma unroll
    for (int t = 0; t < 16; t++) {
        if (t < T) {
            int j = lane + (t << 6);
            float dx = pb[j * 3] - px, dy = pb[j * 3 + 1] - py, dz = pb[j * 3 + 2] - pz;
            d2v[t] = dx * dx + dy * dy + dz * dz;
        } else {
            d2v[t] = 1e30f;
        }
    }
    for (int r = 0; r < KNN; r++) {
        float bv0 = d2v[0];  int bt0 = 0;
        float bv1 = d2v[4];  int bt1 = 4;
        float bv2 = d2v[8];  int bt2 = 8;
        float bv3 = d2v[12]; int bt3 = 12;
        #pragma unroll
        for (int t = 1; t < 4; t++) {
            if (d2v[t]      < bv0) { bv0 = d2v[t];      bt0 = t; }
            if (d2v[4 + t]  < bv1) { bv1 = d2v[4 + t];  bt1 = 4 + t; }
            if (d2v[8 + t]  < bv2) { bv2 = d2v[8 + t];  bt2 = 8 + t; }
            if (d2v[12 + t] < bv3) { bv3 = d2v[12 + t]; bt3 = 12 + t; }
        }
        if (bv1 < bv0) { bv0 = bv1; bt0 = bt1; }
        if (bv3 < bv2) { bv2 = bv3; bt2 = bt3; }
        if (bv2 < bv0) { bv0 = bv2; bt0 = bt2; }
        float bv = bv0;
        int bidx = lane + (bt0 << 6);
        for (int off = 32; off; off >>= 1) {
            float ov = __shfl_xor(bv, off);
            int oi = __shfl_xor(bidx, off);
            if (ov < bv || (ov == bv && oi < bidx)) { bv = ov; bidx = oi; }
        }
        bool win = (bidx & 63) == lane;
        int wt = bidx >> 6;
        #pragma unroll
        for (int t = 0; t < 16; t++)
            if (win && t == wt) d2v[t] = 1e30f;
        if (lane == 0) {
            knn[(size_t)wv * KNN + r] = b * n + bidx;
            atomicAdd(&deg[b * n + bidx], 1);
        }
    }
}

// ---------------- CSR by dst ----------------
__global__ __launch_bounds__(1024) void scan_k(const int* __restrict__ deg, int* __restrict__ off,
                                               int* __restrict__ cur, int NB) {
    __shared__ int part[1024];
    int t = threadIdx.x;
    int per = NB >> 10;
    int base = t * per;
    int s = 0;
    for (int i = 0; i < per; i++) s += deg[base + i] + KNN + 1;
    part[t] = s; __syncthreads();
    for (int d = 1; d < 1024; d <<= 1) {
        int v = (t >= d) ? part[t - d] : 0;
        __syncthreads();
        part[t] += v;
        __syncthreads();
    }
    int prefix = (t > 0) ? part[t - 1] : 0;
    for (int i = 0; i < per; i++) {
        off[base + i] = prefix; cur[base + i] = prefix; prefix += deg[base + i] + KNN + 1;
    }
    if (t == 1023) off[NB] = part[1023];
}
__global__ void fill_eids_k(const int* __restrict__ knn, int NB, int E,
                            int* __restrict__ cur, int* __restrict__ eids,
                            int* __restrict__ dsts) {
    int e = blockIdx.x * 256 + threadIdx.x;
    if (e >= E) return;
    int dst = decode_dst(e, NB * KNN, knn);
    int p = atomicAdd(&cur[dst], 1);
    eids[p] = e;
    dsts[p] = dst;
}
// per slot: rank by edge id within segment (deterministic), inline edge-MLP, write src/ew sorted
__global__ void rank_gather_k(const int* __restrict__ eids, const int* __restrict__ dsts,
                              const int* __restrict__ off, const int* __restrict__ knn,
                              const float* __restrict__ pos, int NB, int E,
                              const float* __restrict__ w1, const float* __restrict__ b1,
                              const float* __restrict__ w2, const float* __restrict__ b2,
                              int* __restrict__ srcs, float* __restrict__ ews) {
    int o = blockIdx.x * 256 + threadIdx.x;
    if (o >= E) return;
    int e = eids[o];
    int d = dsts[o];
    int o0 = off[d], o1 = off[d + 1];
    int rank = 0;
    for (int q = o0; q < o1; q++) rank += (eids[q] < e);
    int src = decode_src(e, NB * KNN, knn);
    float dx = pos[src * 3] - pos[d * 3];
    float dy = pos[src * 3 + 1] - pos[d * 3 + 1];
    float dz = pos[src * 3 + 2] - pos[d * 3 + 2];
    float d2 = dx * dx + dy * dy + dz * dz;
    float dd = d2 > 0.f ? sqrtf(d2) : 0.f;
    float acc = b2[0];
    #pragma unroll
    for (int k = 0; k < 32; k++) {
        float hh = fmaxf(dd * w1[k] + b1[k], 0.f);
        acc += hh * w2[k];
    }
    srcs[o0 + rank] = src;
    ews[o0 + rank] = fmaxf(acc, 0.f);
}

// pack all 4 layers W^T bf16: BT[layer][n][k]
__global__ void wcvt_all_k(const float* __restrict__ Wl, const float* __restrict__ Wr,
                           ushortT* __restrict__ BT) {
    int i = blockIdx.x * 256 + threadIdx.x;
    if (i >= 4 * 128 * 768) return;
    int layer = i / 98304, rem = i % 98304;
    int k = rem / 768, n = rem % 768;
    const float* W = (n < 384) ? (Wl + (size_t)layer * 128 * 384) : (Wr + (size_t)layer * 128 * 384);
    int nn = (n < 384) ? n : n - 384;
    BT[(size_t)layer * 98304 + (size_t)n * 128 + k] = f2bf(W[k * 384 + nn]);
}

// ---------------- MFMA bf16 GEMM: C[M,768] = A[M,128] @ W  (BT = W^T bf16) ----------------
__global__ __launch_bounds__(256) void gemm_mfma_k(const ushortT* __restrict__ A,
                                                   const ushortT* __restrict__ BT,
                                                   ushortT* __restrict__ C, int M) {
    __shared__ ushortT As[128 * 128];
    __shared__ ushortT Bs[128 * 128];
    int nb = blockIdx.x % 6, mb = blockIdx.x / 6;
    int row0 = mb * 128, col0 = nb * 128;
    int tid = threadIdx.x;
    #pragma unroll
    for (int it = 0; it < 8; it++) {
        int idx = tid + it * 256;          // 16B units
        int row = idx >> 4, seg = idx & 15;
        int byte = (row * 256 + seg * 16) ^ ((row & 7) << 4);
        *(float4*)((char*)As + byte) =
            *(const float4*)((const char*)(A + (size_t)(row0 + row) * 128) + seg * 16);
        *(float4*)((char*)Bs + byte) =
            *(const float4*)((const char*)(BT + (size_t)(col0 + row) * 128) + seg * 16);
    }
    __syncthreads();
    int wave = tid >> 6, lane = tid & 63;
    int wr = wave >> 1, wc = wave & 1;
    f32x4 acc[4][4] = {};
    int lrow = lane & 15;
    int lkb = (lane >> 4) * 16;
    #pragma unroll
    for (int ks = 0; ks < 4; ks++) {
        short8 af[4], bfr[4];
        #pragma unroll
        for (int m = 0; m < 4; m++) {
            int row = wr * 64 + m * 16 + lrow;
            int byte = (row * 256 + ks * 64 + lkb) ^ ((row & 7) << 4);
            af[m] = *(short8*)((char*)As + byte);
        }
        #pragma unroll
        for (int n = 0; n < 4; n++) {
            int col = wc * 64 + n * 16 + lrow;
            int byte = (col * 256 + ks * 64 + lkb) ^ ((col & 7) << 4);
            bfr[n] = *(short8*)((char*)Bs + byte);
        }
        #pragma unroll
        for (int m = 0; m < 4; m++)
            #pragma unroll
            for (int n = 0; n < 4; n++)
                acc[m][n] = __builtin_amdgcn_mfma_f32_16x16x32_bf16(af[m], bfr[n], acc[m][n], 0, 0, 0);
    }
    #pragma unroll
    for (int m = 0; m < 4; m++)
        #pragma unroll
        for (int n = 0; n < 4; n++) {
            int r0 = row0 + wr * 64 + m * 16 + (lane >> 4) * 4;
            int c = col0 + wc * 64 + n * 16 + (lane & 15);
            #pragma unroll
            for (int j = 0; j < 4; j++)
                C[(size_t)(r0 + j) * 768 + c] = f2bf(acc[m][n][j]);
        }
}

// ---------------- fused GAT: persistent grid, half-wave, 2-edge unroll (4 edges in flight) ----
__global__ __launch_bounds__(256) void gat_fused_k(
        const float* __restrict__ hin, const ushortT* __restrict__ xlr,
        const int* __restrict__ off, const int* __restrict__ srcs,
        const float* __restrict__ ews, int NB, int n,
        const float* __restrict__ We, const float* __restrict__ att,
        const float* __restrict__ bias, float* __restrict__ hout) {
    int bpg = n >> 2;
    int nslots = NB >> 2;
    int lane = threadIdx.x & 63;
    int l = lane & 31, half = lane >> 5;
    int wid = threadIdx.x >> 6;
    for (int sb = blockIdx.x; sb < nslots; sb += 2048) {
        int xcd = sb & 7, slot = sb >> 3;
        int gid = xcd + 8 * (slot / bpg);
        int node = gid * n + (slot % bpg) * 4 + wid;
        if (node >= NB) continue;
        f32x2 weP[3][2], atP[3][2], xrP[3][2];
        const ushortT* xrp = xlr + (size_t)node * 768 + 384;
        #pragma unroll
        for (int j = 0; j < 3; j++) {
            float4 wv = *(const float4*)(We + j * 128 + l * 4);
            float4 av = *(const float4*)(att + j * 128 + l * 4);
            uint2 u = *(const uint2*)(xrp + j * 128 + l * 4);
            weP[j][0] = f32x2{wv.x, wv.y}; weP[j][1] = f32x2{wv.z, wv.w};
            atP[j][0] = f32x2{av.x, av.y}; atP[j][1] = f32x2{av.z, av.w};
            xrP[j][0] = f32x2{__uint_as_float(u.x << 16), __uint_as_float(u.x & 0xFFFF0000u)};
            xrP[j][1] = f32x2{__uint_as_float(u.y << 16), __uint_as_float(u.y & 0xFFFF0000u)};
        }
        float d[3] = {0.f, 0.f, 0.f};
        f32x2 acc[3][2] = {};
        int o0 = off[node], o1 = off[node + 1];
        for (int o = o0 + half; o < o1; o += 4) {
            int oB = o + 2;
            bool hasB = oB < o1;
            int srcA = srcs[o];
            float wA = ews[o];
            int srcB = hasB ? srcs[oB] : srcA;
            float wB = hasB ? ews[oB] : 0.f;
            const ushortT* plA = xlr + (size_t)srcA * 768;
            const ushortT* plB = xlr + (size_t)srcB * 768;
            float pA[3], pB[3];
            f32x2 xvA[3][2], xvB[3][2];
            #pragma unroll
            for (int j = 0; j < 3; j++) {
                uint2 uA = *(const uint2*)(plA + j * 128 + l * 4);
                uint2 uB = *(const uint2*)(plB + j * 128 + l * 4);
                f32x2 a0 = {__uint_as_float(uA.x << 16), __uint_as_float(uA.x & 0xFFFF0000u)};
                f32x2 a1 = {__uint_as_float(uA.y << 16), __uint_as_float(uA.y & 0xFFFF0000u)};
                f32x2 b0 = {__uint_as_float(uB.x << 16), __uint_as_float(uB.x & 0xFFFF0000u)};
                f32x2 b1 = {__uint_as_float(uB.y << 16), __uint_as_float(uB.y & 0xFFFF0000u)};
                xvA[j][0] = a0; xvA[j][1] = a1;
                xvB[j][0] = b0; xvB[j][1] = b1;
                f32x2 zA0 = a0 + (xrP[j][0] + wA * weP[j][0]);
                f32x2 zA1 = a1 + (xrP[j][1] + wA * weP[j][1]);
                f32x2 zB0 = b0 + (xrP[j][0] + wB * weP[j][0]);
                f32x2 zB1 = b1 + (xrP[j][1] + wB * weP[j][1]);
                zA0 = __builtin_elementwise_max(zA0, zA0 * 0.2f);
                zA1 = __builtin_elementwise_max(zA1, zA1 * 0.2f);
                zB0 = __builtin_elementwise_max(zB0, zB0 * 0.2f);
                zB1 = __builtin_elementwise_max(zB1, zB1 * 0.2f);
                f32x2 pvA = zA0 * atP[j][0] + zA1 * atP[j][1];
                f32x2 pvB = zB0 * atP[j][0] + zB1 * atP[j][1];
                pA[j] = pvA.x + pvA.y;
                pB[j] = pvB.x + pvB.y;
            }
            if (!hasB) { pB[0] = -1e30f; pB[1] = -1e30f; pB[2] = -1e30f; }
            #pragma unroll
            for (int sh = 16; sh; sh >>= 1) {
                pA[0] += __shfl_xor(pA[0], sh);
                pA[1] += __shfl_xor(pA[1], sh);
                pA[2] += __shfl_xor(pA[2], sh);
                pB[0] += __shfl_xor(pB[0], sh);
                pB[1] += __shfl_xor(pB[1], sh);
                pB[2] += __shfl_xor(pB[2], sh);
            }
            #pragma unroll
            for (int j = 0; j < 3; j++) {
                float eA = __expf(fminf(pA[j], 60.f));
                float eB = __expf(fminf(pB[j], 60.f));
                d[j] += eA + eB;
                acc[j][0] += eA * xvA[j][0] + eB * xvB[j][0];
                acc[j][1] += eA * xvA[j][1] + eB * xvB[j][1];
            }
        }
        #pragma unroll
        for (int j = 0; j < 3; j++) {
            d[j] += __shfl_xor(d[j], 32);
            #pragma unroll
            for (int pr = 0; pr < 2; pr++) {
                acc[j][pr].x += __shfl_xor(acc[j][pr].x, 32);
                acc[j][pr].y += __shfl_xor(acc[j][pr].y, 32);
            }
        }
        if (half == 0) {
            float4 bv = *(const float4*)(bias + l * 4);
            float4 hv = *(const float4*)(hin + (size_t)node * H + l * 4);
            float i0 = 1.f / d[0], i1 = 1.f / d[1], i2 = 1.f / d[2];
            float av[4] = {acc[0][0].x, acc[0][0].y, acc[0][1].x, acc[0][1].y};
            float bv1[4] = {acc[1][0].x, acc[1][0].y, acc[1][1].x, acc[1][1].y};
            float cv[4] = {acc[2][0].x, acc[2][0].y, acc[2][1].x, acc[2][1].y};
            float bb[4] = {bv.x, bv.y, bv.z, bv.w};
            float hh[4] = {hv.x, hv.y, hv.z, hv.w};
            float ob[4];
            #pragma unroll
            for (int q = 0; q < 4; q++) {
                float g = (av[q] * i0 + bv1[q] * i1 + cv[q] * i2) * (1.f / 3.f) + bb[q];
                float xa = hh[q] + g;
                ob[q] = xa / (1.f + __expf(-xa));
            }
            *(float4*)(hout + (size_t)node * H + l * 4) = make_float4(ob[0], ob[1], ob[2], ob[3]);
        }
    }
}

// ---------------- output head ----------------
__global__ void head_k(const float* __restrict__ cat, const float* __restrict__ W1,
                       const float* __restrict__ b1, const float* __restrict__ W2,
                       const float* __restrict__ b2, float* __restrict__ outp) {
    int b = blockIdx.x, d = threadIdx.x; // 128
    __shared__ float cs[768];
    __shared__ float o1[128];
    for (int i = d; i < 768; i += 128) cs[i] = cat[b * 768 + i];
    __syncthreads();
    float s = b1[d];
    for (int c = 0; c < 768; c++) s += cs[c] * W1[c * 128 + d];
    o1[d] = fmaxf(s, 0.f);
    __syncthreads();
    float s2 = b2[d];
    for (int c = 0; c < 128; c++) s2 += o1[c] * W2[c * 128 + d];
    outp[b * 128 + d] = s2;
}

// ---------------- driver ----------------
extern "C" void kernel_launch(void* const* d_in, const int* in_sizes, int n_in,
                              void* d_out, int out_size, void* d_ws, size_t ws_size,
                              hipStream_t stream) {
    (void)in_sizes; (void)n_in; (void)out_size; (void)ws_size;
    const float* x        = (const float*)d_in[0];
    const float* pos      = (const float*)d_in[1];
    const float* bn_g     = (const float*)d_in[2];
    const float* bn_b     = (const float*)d_in[3];
    const float* conv_Wl  = (const float*)d_in[4];
    const float* conv_Wr  = (const float*)d_in[5];
    const float* conv_We  = (const float*)d_in[6];
    const float* conv_att = (const float*)d_in[7];
    const float* conv_bias= (const float*)d_in[8];
    const float* pool_w   = (const float*)d_in[9];
    const float* gate_w   = (const float*)d_in[10];
    const float* gate_b   = (const float*)d_in[11];
    const float* ro_w     = (const float*)d_in[12];
    const float* ro_b     = (const float*)d_in[13];
    const float* em_w1    = (const float*)d_in[14];
    const float* em_b1    = (const float*)d_in[15];
    const float* em_w2    = (const float*)d_in[16];
    const float* em_b2    = (const float*)d_in[17];
    const float* out_w1   = (const float*)d_in[18];
    const float* out_b1   = (const float*)d_in[19];
    const float* out_w2   = (const float*)d_in[20];
    const float* out_b2   = (const float*)d_in[21];
    float* outp = (float*)d_out;

    const int E1 = BGR * N1C * KNN * 2 + BGR * N1C; // 344064
    char* ws = (char*)d_ws;
    size_t o = 0;
    auto take = [&](size_t bytes) -> char* {
        char* p = ws + o;
        o += (bytes + 255) & ~(size_t)255;
        return p;
    };
    ushortT* xlrb = (ushortT*)take((size_t)16384 * 768 * 2);
    ushortT* hbf  = (ushortT*)take((size_t)16384 * 128 * 2);
    ushortT* wbt4 = (ushortT*)take((size_t)4 * 768 * 128 * 2);
    float* h0     = (float*)take((size_t)32768 * 128 * 4);
    float* h1a    = (float*)take((size_t)16384 * 128 * 4);
    float* h1b    = (float*)take((size_t)16384 * 128 * 4);
    float* h2a    = (float*)take((size_t)8192 * 128 * 4);
    float* h2b    = (float*)take((size_t)8192 * 128 * 4);
    float* ews    = (float*)take((size_t)E1 * 4);
    float* pos1   = (float*)take((size_t)16384 * 3 * 4);
    float* pos2   = (float*)take((size_t)8192 * 3 * 4);
    float* plog   = (float*)take((size_t)32768 * 4);
    float* vals   = (float*)take((size_t)16384 * 4);
    float* apart  = (float*)take((size_t)16 * 32 * 128 * 4);
    float* catb   = (float*)take((size_t)12288 * 4);
    float* stats  = (float*)take((size_t)256 * 4);
    float* parts  = (float*)take((size_t)128 * 256 * 4);
    int* knnb     = (int*)take((size_t)163840 * 4);
    int* permb    = (int*)take((size_t)16384 * 4);
    int* degb     = (int*)take((size_t)16385 * 4);
    int* offb     = (int*)take((size_t)16385 * 4);
    int* curb     = (int*)take((size_t)16384 * 4);
    int* eidsb    = (int*)take((size_t)E1 * 4);
    int* dstsb    = (int*)take((size_t)E1 * 4);
    int* srcsb    = (int*)take((size_t)E1 * 4);

    auto run_bn = [&](const float* in, float* out2, ushortT* bf, int rows, int layer) {
        colstats_k<<<128, 256, 0, stream>>>(in, rows, parts);
        colreduce_k<<<1, 256, 0, stream>>>(parts, stats);
        bn_apply_k<<<(rows * 128) / 256, 256, 0, stream>>>(in, out2, bf, stats, bn_g + layer * H, bn_b + layer * H, rows);
    };
    auto run_pool = [&](const float* hsrc, const float* possrc, float* hdst, float* posdst,
                        int n, int keep, int p) {
        int rows = BGR * n;
        matvec_k<<<rows / 4, 256, 0, stream>>>(hsrc, pool_w + p * H, nullptr, plog, rows);
        pool_rank_k<<<BGR * (n / 64), 256, 0, stream>>>(plog, n, keep, permb, vals);
        pool_gather_k<<<(BGR * keep * 128) / 256, 256, 0, stream>>>(hsrc, possrc, permb, vals, hdst, hbf, posdst, BGR * keep);
    };
    auto run_readout = [&](const float* hsrc, int n, int g, int catoff) {
        int rows = BGR * n;
        int chunks = n / 64;
        matvec_k<<<rows / 4, 256, 0, stream>>>(hsrc, gate_w + g * H, gate_b + g, plog, rows);
        att_partial_k<<<BGR * chunks, 256, 0, stream>>>(hsrc, plog, n, apart);
        ro_gemm_k<<<BGR, 256, 0, stream>>>(apart, chunks, ro_w + (size_t)g * H * 256, ro_b + g * 256, catb, catoff);
    };
    auto build_graph = [&](const float* posb, int n, int st) {
        int NB = BGR * n, E = NB * KNN * 2 + NB;
        hipMemsetAsync(degb, 0, (size_t)NB * 4, stream);
        knn_k<<<NB / 4, 256, 0, stream>>>(posb, n, knnb, degb);
        scan_k<<<1, 1024, 0, stream>>>(degb, offb, curb, NB);
        fill_eids_k<<<E / 256, 256, 0, stream>>>(knnb, NB, E, curb, eidsb, dstsb);
        rank_gather_k<<<E / 256, 256, 0, stream>>>(eidsb, dstsb, offb, knnb, posb, NB, E,
                                                   em_w1 + st * 32, em_b1 + st * 32,
                                                   em_w2 + st * 32, em_b2 + st, srcsb, ews);
    };
    auto run_gat = [&](const float* hin, float* hout, int NB, int n, int layer) {
        gemm_mfma_k<<<(NB / 128) * 6, 256, 0, stream>>>(hbf, wbt4 + (size_t)layer * 98304, xlrb, NB);
        int nslots = NB / 4;
        int grid = nslots < 2048 ? nslots : 2048;
        gat_fused_k<<<grid, 256, 0, stream>>>(hin, xlrb, offb, srcsb, ews, NB, n,
                                              conv_We + layer * 384, conv_att + layer * 384,
                                              conv_bias + layer * H, hout);
    };

    wcvt_all_k<<<1536, 256, 0, stream>>>(conv_Wl, conv_Wr, wbt4);
    run_bn(x, h0, nullptr, BGR * N0C, 0);
    run_pool(h0, pos, h1a, pos1, N0C, N1C, 0);
    run_readout(h1a, N1C, 0, 512);
    build_graph(pos1, N1C, 0);
    run_gat(h1a, h1b, BGR * N1C, N1C, 0);
    run_bn(h1b, h1a, hbf, BGR * N1C, 1);
    run_gat(h1a, h1b, BGR * N1C, N1C, 1);
    run_bn(h1b, h1a, nullptr, BGR * N1C, 2);
    run_pool(h1a, pos1, h2a, pos2, N1C, N2C, 1);
    run_readout(h2a, N2C, 1, 256);
    build_graph(pos2, N2C, 1);
    run_gat(h2a, h2b, BGR * N2C, N2C, 2);
    run_bn(h2b, h2a, hbf, BGR * N2C, 3);
    run_gat(h2a, h2b, BGR * N2C, N2C, 3);
    run_bn(h2b, h2a, nullptr, BGR * N2C, 4);
    run_readout(h2a, N2C, 2, 0);
    head_k<<<BGR, 128, 0, stream>>>(catb, out_w1, out_b1, out_w2, out_b2, outp);
}

// Round 16
// 622.554 us; speedup vs baseline: 1.1776x; 1.1776x over previous
//
#include <hip/hip_runtime.h>
#include <math.h>

#define H 128
#define NHEADS 3
#define BGR 16
#define N0C 2048
#define N1C 1024
#define N2C 512
#define KNN 10
#define EPSV 1e-5f

typedef unsigned short ushortT;
typedef __attribute__((ext_vector_type(8))) short short8;
typedef __attribute__((ext_vector_type(4))) short s16x4;
typedef __attribute__((ext_vector_type(4))) float f32x4;
typedef __attribute__((ext_vector_type(2))) float f32x2;

static __device__ __forceinline__ unsigned short f2bf(float f) {
    unsigned u = __float_as_uint(f);
    unsigned r = (u + 0x7FFF + ((u >> 16) & 1)) >> 16;
    return (unsigned short)r;
}
static __device__ __forceinline__ float bf2f(unsigned short s) {
    return __uint_as_float(((unsigned)s) << 16);
}

// ---------------- decode edge -> (src,dst) from knn table ----------------
static __device__ __forceinline__ int decode_src(int e, int BNK, const int* __restrict__ knn) {
    if (e < BNK) return knn[e];
    int f = e - BNK;
    if (f < BNK) return f / KNN;
    return f - BNK;
}
static __device__ __forceinline__ int decode_dst(int e, int BNK, const int* __restrict__ knn) {
    if (e < BNK) return e / KNN;
    int f = e - BNK;
    if (f < BNK) return knn[f];
    return f - BNK;
}

// ---------------- batchnorm (optionally fused row-dot -> plog) ----------------
__global__ void colstats_k(const float* __restrict__ xin, int rows, float* __restrict__ part) {
    int c = threadIdx.x & 127, rr = threadIdx.x >> 7;
    float s = 0.f, q = 0.f;
    for (int r = blockIdx.x * 2 + rr; r < rows; r += 256) {
        float v = xin[(size_t)r * H + c];
        s += v; q += v * v;
    }
    __shared__ float ls[256], lq[256];
    ls[threadIdx.x] = s; lq[threadIdx.x] = q;
    __syncthreads();
    if (rr == 0) {
        part[blockIdx.x * 256 + c]       = s + ls[threadIdx.x + 128];
        part[blockIdx.x * 256 + 128 + c] = q + lq[threadIdx.x + 128];
    }
}
__global__ void colreduce_k(const float* __restrict__ part, float* __restrict__ stats) {
    int t = threadIdx.x; // 256
    float s = 0.f;
    for (int p = 0; p < 128; p++) s += part[p * 256 + t];
    stats[t] = s;
}
// block = 256 threads = 2 rows (rows*H always multiple of 256 here)
__global__ void bn_apply_k(const float* __restrict__ xin, float* __restrict__ xout,
                           ushortT* __restrict__ bfout,
                           const float* __restrict__ stats, const float* __restrict__ g,
                           const float* __restrict__ b,
                           const float* __restrict__ gw, const float* __restrict__ gbp,
                           float* __restrict__ plog, int rows) {
    int idx = blockIdx.x * 256 + threadIdx.x;
    int t = threadIdx.x;
    int c = idx & 127;
    float mean = stats[c] / rows;
    float var = stats[128 + c] / rows - mean * mean;
    float v = (xin[idx] - mean) * rsqrtf(var + EPSV) * g[c] + b[c];
    xout[idx] = v;
    if (bfout) bfout[idx] = f2bf(v);
    if (gw) {
        __shared__ float red[256];
        red[t] = v * gw[c];
        __syncthreads();
        int hh = t & 127;
        for (int st = 64; st; st >>= 1) {
            if (hh < st) red[t] += red[t + st];
            __syncthreads();
        }
        if (hh == 0) plog[idx >> 7] = red[t] + (gbp ? gbp[0] : 0.f);
    }
}

// ---------------- top-k pool: rank raw logits, 4 threads per i ----------------
__global__ void pool_rank_k(const float* __restrict__ logit, int n, int keep,
                            int* __restrict__ perm, float* __restrict__ vals) {
    __shared__ float s[2048];
    __shared__ float red[256];
    int groups = n >> 6;
    int b = blockIdx.x / groups, ch = blockIdx.x % groups;
    int t = threadIdx.x; // 256
    const float* L = logit + b * n;
    float mx = -1e30f;
    for (int i = t; i < n; i += 256) { float v = L[i]; s[i] = v; mx = fmaxf(mx, v); }
    red[t] = mx; __syncthreads();
    for (int st = 128; st; st >>= 1) { if (t < st) red[t] = fmaxf(red[t], red[t + st]); __syncthreads(); }
    mx = red[0]; __syncthreads();
    float sm = 0.f;
    for (int i = t; i < n; i += 256) sm += __expf(s[i] - mx);
    red[t] = sm; __syncthreads();
    for (int st = 128; st; st >>= 1) { if (t < st) red[t] += red[t + st]; __syncthreads(); }
    float inv = 1.f / red[0];
    __syncthreads();
    int il = t >> 2, q = t & 3;
    int i = ch * 64 + il;
    float si = s[i];
    int cnt = 0;
    const float4* s4 = (const float4*)s;
    int K4 = n >> 4;
    #pragma unroll 4
    for (int kk = 0; kk < K4; kk++) {
        int jj = kk * 4 + q;
        float4 v = s4[jj];
        int jb = jj * 4;
        cnt += (v.x > si) || (v.x == si && (jb + 0) < i);
        cnt += (v.y > si) || (v.y == si && (jb + 1) < i);
        cnt += (v.z > si) || (v.z == si && (jb + 2) < i);
        cnt += (v.w > si) || (v.w == si && (jb + 3) < i);
    }
    cnt += __shfl_xor(cnt, 1);
    cnt += __shfl_xor(cnt, 2);
    if (q == 0 && cnt < keep) { perm[b * keep + cnt] = b * n + i; vals[b * keep + cnt] = __expf(si - mx) * inv; }
}
// gathers pooled rows; optionally fused gate-dot -> plog (block = 2 rows)
__global__ void pool_gather_k(const float* __restrict__ hsrc, const float* __restrict__ possrc,
                              const int* __restrict__ perm, const float* __restrict__ vals,
                              float* __restrict__ hd, ushortT* __restrict__ bfout,
                              float* __restrict__ posd,
                              const float* __restrict__ gw, const float* __restrict__ gbp,
                              float* __restrict__ plog, int rows) {
    int idx = blockIdx.x * 256 + threadIdx.x;
    int t = threadIdx.x;
    int r = idx >> 7, c = idx & 127;
    int p = perm[r];
    float v = hsrc[(size_t)p * H + c] * vals[r];
    hd[idx] = v;
    bfout[idx] = f2bf(v);
    if (c < 3) posd[r * 3 + c] = possrc[p * 3 + c];
    if (gw) {
        __shared__ float red[256];
        red[t] = v * gw[c];
        __syncthreads();
        int hh = t & 127;
        for (int st = 64; st; st >>= 1) {
            if (hh < st) red[t] += red[t + st];
            __syncthreads();
        }
        if (hh == 0) plog[r] = red[t] + (gbp ? gbp[0] : 0.f);
    }
}

// ---------------- attention readout: softmax fused into weighted column sum ----------------
__global__ void att_partial_k(const float* __restrict__ hsrc, const float* __restrict__ plog,
                              int n, float* __restrict__ part) {
    __shared__ float s[1024];
    __shared__ float red[256];
    int chunks = n >> 6;
    int b = blockIdx.x / chunks, ch = blockIdx.x % chunks;
    int t = threadIdx.x;
    const float* L = plog + b * n;
    float mx = -1e30f;
    for (int i = t; i < n; i += 256) { float v = L[i]; s[i] = v; mx = fmaxf(mx, v); }
    red[t] = mx; __syncthreads();
    for (int st = 128; st; st >>= 1) { if (t < st) red[t] = fmaxf(red[t], red[t + st]); __syncthreads(); }
    mx = red[0]; __syncthreads();
    float sm = 0.f;
    for (int i = t; i < n; i += 256) sm += __expf(s[i] - mx);
    red[t] = sm; __syncthreads();
    for (int st = 128; st; st >>= 1) { if (t < st) red[t] += red[t + st]; __syncthreads(); }
    float inv = 1.f / red[0];
    __syncthreads();
    int c = t & 127, rg = t >> 7;
    int r0 = ch * 64;
    float acc = 0.f;
    for (int i = rg; i < 64; i += 2) {
        int r = r0 + i;
        acc += __expf(s[r] - mx) * inv * hsrc[((size_t)b * n + r) * H + c];
    }
    red[t] = acc; __syncthreads();
    if (rg == 0) part[((size_t)b * chunks + ch) * H + c] = red[c] + red[128 + c];
}
// fused chunk-reduce + [1,128]@[128,256] readout GEMM
__global__ void ro_gemm_k(const float* __restrict__ part, int chunks,
                          const float* __restrict__ w, const float* __restrict__ bias,
                          float* __restrict__ catp, int coff) {
    int b = blockIdx.x, d = threadIdx.x; // 256
    __shared__ float hb[128];
    if (d < 128) {
        float s2 = 0.f;
        for (int ch = 0; ch < chunks; ch++) s2 += part[((size_t)b * chunks + ch) * H + d];
        hb[d] = s2;
    }
    __syncthreads();
    float acc = bias[d];
    for (int c = 0; c < 128; c++) acc += hb[c] * w[c * 256 + d];
    catp[b * 768 + coff + d] = acc;
}

// ---------------- kNN (k=10, includes self) — register-resident, 4-chain argmin ----------------
__global__ void knn_k(const float* __restrict__ pos, int n, int* __restrict__ knn,
                      int* __restrict__ deg) {
    int wv = blockIdx.x * 4 + (threadIdx.x >> 6);
    int lane = threadIdx.x & 63;
    int b = wv / n;
    const float* pb = pos + (size_t)b * n * 3;
    float px = pos[(size_t)wv * 3], py = pos[(size_t)wv * 3 + 1], pz = pos[(size_t)wv * 3 + 2];
    int T = n >> 6;
    float d2v[16];
    #pragma unroll
    for (int t = 0; t < 16; t++) {
        if (t < T) {
            int j = lane + (t << 6);
            float dx = pb[j * 3] - px, dy = pb[j * 3 + 1] - py, dz = pb[j * 3 + 2] - pz;
            d2v[t] = dx * dx + dy * dy + dz * dz;
        } else {
            d2v[t] = 1e30f;
        }
    }
    for (int r = 0; r < KNN; r++) {
        float bv0 = d2v[0];  int bt0 = 0;
        float bv1 = d2v[4];  int bt1 = 4;
        float bv2 = d2v[8];  int bt2 = 8;
        float bv3 = d2v[12]; int bt3 = 12;
        #pragma unroll
        for (int t = 1; t < 4; t++) {
            if (d2v[t]      < bv0) { bv0 = d2v[t];      bt0 = t; }
            if (d2v[4 + t]  < bv1) { bv1 = d2v[4 + t];  bt1 = 4 + t; }
            if (d2v[8 + t]  < bv2) { bv2 = d2v[8 + t];  bt2 = 8 + t; }
            if (d2v[12 + t] < bv3) { bv3 = d2v[12 + t]; bt3 = 12 + t; }
        }
        if (bv1 < bv0) { bv0 = bv1; bt0 = bt1; }
        if (bv3 < bv2) { bv2 = bv3; bt2 = bt3; }
        if (bv2 < bv0) { bv0 = bv2; bt0 = bt2; }
        float bv = bv0;
        int bidx = lane + (bt0 << 6);
        for (int off = 32; off; off >>= 1) {
            float ov = __shfl_xor(bv, off);
            int oi = __shfl_xor(bidx, off);
            if (ov < bv || (ov == bv && oi < bidx)) { bv = ov; bidx = oi; }
        }
        bool win = (bidx & 63) == lane;
        int wt = bidx >> 6;
        #pragma unroll
        for (int t = 0; t < 16; t++)
            if (win && t == wt) d2v[t] = 1e30f;
        if (lane == 0) {
            knn[(size_t)wv * KNN + r] = b * n + bidx;
            atomicAdd(&deg[b * n + bidx], 1);
        }
    }
}

// ---------------- CSR by dst ----------------
__global__ __launch_bounds__(1024) void scan_k(const int* __restrict__ deg, int* __restrict__ off,
                                               int* __restrict__ cur, int NB) {
    __shared__ int part[1024];
    int t = threadIdx.x;
    int per = NB >> 10;
    int base = t * per;
    int s = 0;
    for (int i = 0; i < per; i++) s += deg[base + i] + KNN + 1;
    part[t] = s; __syncthreads();
    for (int d = 1; d < 1024; d <<= 1) {
        int v = (t >= d) ? part[t - d] : 0;
        __syncthreads();
        part[t] += v;
        __syncthreads();
    }
    int prefix = (t > 0) ? part[t - 1] : 0;
    for (int i = 0; i < per; i++) {
        off[base + i] = prefix; cur[base + i] = prefix; prefix += deg[base + i] + KNN + 1;
    }
    if (t == 1023) off[NB] = part[1023];
}
__global__ void fill_eids_k(const int* __restrict__ knn, int NB, int E,
                            int* __restrict__ cur, int* __restrict__ eids,
                            int* __restrict__ dsts) {
    int e = blockIdx.x * 256 + threadIdx.x;
    if (e >= E) return;
    int dst = decode_dst(e, NB * KNN, knn);
    int p = atomicAdd(&cur[dst], 1);
    eids[p] = e;
    dsts[p] = dst;
}
// per slot: rank by edge id within segment (deterministic), inline edge-MLP, write src/ew sorted
__global__ void rank_gather_k(const int* __restrict__ eids, const int* __restrict__ dsts,
                              const int* __restrict__ off, const int* __restrict__ knn,
                              const float* __restrict__ pos, int NB, int E,
                              const float* __restrict__ w1, const float* __restrict__ b1,
                              const float* __restrict__ w2, const float* __restrict__ b2,
                              int* __restrict__ srcs, float* __restrict__ ews) {
    int o = blockIdx.x * 256 + threadIdx.x;
    if (o >= E) return;
    int e = eids[o];
    int d = dsts[o];
    int o0 = off[d], o1 = off[d + 1];
    int rank = 0;
    for (int q = o0; q < o1; q++) rank += (eids[q] < e);
    int src = decode_src(e, NB * KNN, knn);
    float dx = pos[src * 3] - pos[d * 3];
    float dy = pos[src * 3 + 1] - pos[d * 3 + 1];
    float dz = pos[src * 3 + 2] - pos[d * 3 + 2];
    float d2 = dx * dx + dy * dy + dz * dz;
    float dd = d2 > 0.f ? sqrtf(d2) : 0.f;
    float acc = b2[0];
    #pragma unroll
    for (int k = 0; k < 32; k++) {
        float hh = fmaxf(dd * w1[k] + b1[k], 0.f);
        acc += hh * w2[k];
    }
    srcs[o0 + rank] = src;
    ews[o0 + rank] = fmaxf(acc, 0.f);
}

// pack all 4 layers W^T bf16: BT[layer][n][k]
__global__ void wcvt_all_k(const float* __restrict__ Wl, const float* __restrict__ Wr,
                           ushortT* __restrict__ BT) {
    int i = blockIdx.x * 256 + threadIdx.x;
    if (i >= 4 * 128 * 768) return;
    int layer = i / 98304, rem = i % 98304;
    int k = rem / 768, n = rem % 768;
    const float* W = (n < 384) ? (Wl + (size_t)layer * 128 * 384) : (Wr + (size_t)layer * 128 * 384);
    int nn = (n < 384) ? n : n - 384;
    BT[(size_t)layer * 98304 + (size_t)n * 128 + k] = f2bf(W[k * 384 + nn]);
}

// ---------------- MFMA bf16 GEMM: C[M,768] = A[M,128] @ W  (BT = W^T bf16) ----------------
__global__ __launch_bounds__(256) void gemm_mfma_k(const ushortT* __restrict__ A,
                                                   const ushortT* __restrict__ BT,
                                                   ushortT* __restrict__ C, int M) {
    __shared__ ushortT As[128 * 128];
    __shared__ ushortT Bs[128 * 128];
    int nb = blockIdx.x % 6, mb = blockIdx.x / 6;
    int row0 = mb * 128, col0 = nb * 128;
    int tid = threadIdx.x;
    #pragma unroll
    for (int it = 0; it < 8; it++) {
        int idx = tid + it * 256;          // 16B units
        int row = idx >> 4, seg = idx & 15;
        int byte = (row * 256 + seg * 16) ^ ((row & 7) << 4);
        *(float4*)((char*)As + byte) =
            *(const float4*)((const char*)(A + (size_t)(row0 + row) * 128) + seg * 16);
        *(float4*)((char*)Bs + byte) =
            *(const float4*)((const char*)(BT + (size_t)(col0 + row) * 128) + seg * 16);
    }
    __syncthreads();
    int wave = tid >> 6, lane = tid & 63;
    int wr = wave >> 1, wc = wave & 1;
    f32x4 acc[4][4] = {};
    int lrow = lane & 15;
    int lkb = (lane >> 4) * 16;
    #pragma unroll
    for (int ks = 0; ks < 4; ks++) {
        short8 af[4], bfr[4];
        #pragma unroll
        for (int m = 0; m < 4; m++) {
            int row = wr * 64 + m * 16 + lrow;
            int byte = (row * 256 + ks * 64 + lkb) ^ ((row & 7) << 4);
            af[m] = *(short8*)((char*)As + byte);
        }
        #pragma unroll
        for (int n = 0; n < 4; n++) {
            int col = wc * 64 + n * 16 + lrow;
            int byte = (col * 256 + ks * 64 + lkb) ^ ((col & 7) << 4);
            bfr[n] = *(short8*)((char*)Bs + byte);
        }
        #pragma unroll
        for (int m = 0; m < 4; m++)
            #pragma unroll
            for (int n = 0; n < 4; n++)
                acc[m][n] = __builtin_amdgcn_mfma_f32_16x16x32_bf16(af[m], bfr[n], acc[m][n], 0, 0, 0);
    }
    #pragma unroll
    for (int m = 0; m < 4; m++)
        #pragma unroll
        for (int n = 0; n < 4; n++) {
            int r0 = row0 + wr * 64 + m * 16 + (lane >> 4) * 4;
            int c = col0 + wc * 64 + n * 16 + (lane & 15);
            #pragma unroll
            for (int j = 0; j < 4; j++)
                C[(size_t)(r0 + j) * 768 + c] = f2bf(acc[m][n][j]);
        }
}

// ---------------- fused GAT: persistent grid, half-wave per edge, packed-f32x2 ----------------
__global__ __launch_bounds__(256) void gat_fused_k(
        const float* __restrict__ hin, const ushortT* __restrict__ xlr,
        const int* __restrict__ off, const int* __restrict__ srcs,
        const float* __restrict__ ews, int NB, int n,
        const float* __restrict__ We, const float* __restrict__ att,
        const float* __restrict__ bias, float* __restrict__ hout) {
    int bpg = n >> 2;
    int nslots = NB >> 2;
    int lane = threadIdx.x & 63;
    int l = lane & 31, half = lane >> 5;
    int wid = threadIdx.x >> 6;
    for (int sb = blockIdx.x; sb < nslots; sb += 2048) {
        int xcd = sb & 7, slot = sb >> 3;
        int gid = xcd + 8 * (slot / bpg);
        int node = gid * n + (slot % bpg) * 4 + wid;
        if (node >= NB) continue;
        f32x2 weP[3][2], atP[3][2], xrP[3][2];
        const ushortT* xrp = xlr + (size_t)node * 768 + 384;
        #pragma unroll
        for (int j = 0; j < 3; j++) {
            float4 wv = *(const float4*)(We + j * 128 + l * 4);
            float4 av = *(const float4*)(att + j * 128 + l * 4);
            uint2 u = *(const uint2*)(xrp + j * 128 + l * 4);
            weP[j][0] = f32x2{wv.x, wv.y}; weP[j][1] = f32x2{wv.z, wv.w};
            atP[j][0] = f32x2{av.x, av.y}; atP[j][1] = f32x2{av.z, av.w};
            xrP[j][0] = f32x2{__uint_as_float(u.x << 16), __uint_as_float(u.x & 0xFFFF0000u)};
            xrP[j][1] = f32x2{__uint_as_float(u.y << 16), __uint_as_float(u.y & 0xFFFF0000u)};
        }
        float d[3] = {0.f, 0.f, 0.f};
        f32x2 acc[3][2] = {};
        int o0 = off[node], o1 = off[node + 1];
        int o = o0 + half;
        int src = 0; float w = 0.f;
        if (o < o1) { src = srcs[o]; w = ews[o]; }
        while (o < o1) {
            int on = o + 2;
            int src_n = 0; float w_n = 0.f;
            if (on < o1) { src_n = srcs[on]; w_n = ews[on]; }
            const ushortT* pl = xlr + (size_t)src * 768;
            float p[3];
            f32x2 xv[3][2];
            #pragma unroll
            for (int j = 0; j < 3; j++) {
                uint2 u = *(const uint2*)(pl + j * 128 + l * 4);
                f32x2 x0 = {__uint_as_float(u.x << 16), __uint_as_float(u.x & 0xFFFF0000u)};
                f32x2 x1 = {__uint_as_float(u.y << 16), __uint_as_float(u.y & 0xFFFF0000u)};
                xv[j][0] = x0; xv[j][1] = x1;
                f32x2 z0 = x0 + (xrP[j][0] + w * weP[j][0]);
                f32x2 z1 = x1 + (xrP[j][1] + w * weP[j][1]);
                z0 = __builtin_elementwise_max(z0, z0 * 0.2f);
                z1 = __builtin_elementwise_max(z1, z1 * 0.2f);
                f32x2 pv = z0 * atP[j][0] + z1 * atP[j][1];
                p[j] = pv.x + pv.y;
            }
            #pragma unroll
            for (int sh = 16; sh; sh >>= 1) {
                p[0] += __shfl_xor(p[0], sh);
                p[1] += __shfl_xor(p[1], sh);
                p[2] += __shfl_xor(p[2], sh);
            }
            #pragma unroll
            for (int j = 0; j < 3; j++) {
                float e = __expf(fminf(p[j], 60.f));
                d[j] += e;
                acc[j][0] += e * xv[j][0];
                acc[j][1] += e * xv[j][1];
            }
            o = on; src = src_n; w = w_n;
        }
        #pragma unroll
        for (int j = 0; j < 3; j++) {
            d[j] += __shfl_xor(d[j], 32);
            #pragma unroll
            for (int pr = 0; pr < 2; pr++) {
                acc[j][pr].x += __shfl_xor(acc[j][pr].x, 32);
                acc[j][pr].y += __shfl_xor(acc[j][pr].y, 32);
            }
        }
        if (half == 0) {
            float4 bv = *(const float4*)(bias + l * 4);
            float4 hv = *(const float4*)(hin + (size_t)node * H + l * 4);
            float i0 = 1.f / d[0], i1 = 1.f / d[1], i2 = 1.f / d[2];
            float av[4] = {acc[0][0].x, acc[0][0].y, acc[0][1].x, acc[0][1].y};
            float bv1[4] = {acc[1][0].x, acc[1][0].y, acc[1][1].x, acc[1][1].y};
            float cv[4] = {acc[2][0].x, acc[2][0].y, acc[2][1].x, acc[2][1].y};
            float bb[4] = {bv.x, bv.y, bv.z, bv.w};
            float hh[4] = {hv.x, hv.y, hv.z, hv.w};
            float ob[4];
            #pragma unroll
            for (int q = 0; q < 4; q++) {
                float g = (av[q] * i0 + bv1[q] * i1 + cv[q] * i2) * (1.f / 3.f) + bb[q];
                float xa = hh[q] + g;
                ob[q] = xa / (1.f + __expf(-xa));
            }
            *(float4*)(hout + (size_t)node * H + l * 4) = make_float4(ob[0], ob[1], ob[2], ob[3]);
        }
    }
}

// ---------------- output head ----------------
__global__ void head_k(const float* __restrict__ cat, const float* __restrict__ W1,
                       const float* __restrict__ b1, const float* __restrict__ W2,
                       const float* __restrict__ b2, float* __restrict__ outp) {
    int b = blockIdx.x, d = threadIdx.x; // 128
    __shared__ float cs[768];
    __shared__ float o1[128];
    for (int i = d; i < 768; i += 128) cs[i] = cat[b * 768 + i];
    __syncthreads();
    float s = b1[d];
    for (int c = 0; c < 768; c++) s += cs[c] * W1[c * 128 + d];
    o1[d] = fmaxf(s, 0.f);
    __syncthreads();
    float s2 = b2[d];
    for (int c = 0; c < 128; c++) s2 += o1[c] * W2[c * 128 + d];
    outp[b * 128 + d] = s2;
}

// ---------------- driver ----------------
extern "C" void kernel_launch(void* const* d_in, const int* in_sizes, int n_in,
                              void* d_out, int out_size, void* d_ws, size_t ws_size,
                              hipStream_t stream) {
    (void)in_sizes; (void)n_in; (void)out_size; (void)ws_size;
    const float* x        = (const float*)d_in[0];
    const float* pos      = (const float*)d_in[1];
    const float* bn_g     = (const float*)d_in[2];
    const float* bn_b     = (const float*)d_in[3];
    const float* conv_Wl  = (const float*)d_in[4];
    const float* conv_Wr  = (const float*)d_in[5];
    const float* conv_We  = (const float*)d_in[6];
    const float* conv_att = (const float*)d_in[7];
    const float* conv_bias= (const float*)d_in[8];
    const float* pool_w   = (const float*)d_in[9];
    const float* gate_w   = (const float*)d_in[10];
    const float* gate_b   = (const float*)d_in[11];
    const float* ro_w     = (const float*)d_in[12];
    const float* ro_b     = (const float*)d_in[13];
    const float* em_w1    = (const float*)d_in[14];
    const float* em_b1    = (const float*)d_in[15];
    const float* em_w2    = (const float*)d_in[16];
    const float* em_b2    = (const float*)d_in[17];
    const float* out_w1   = (const float*)d_in[18];
    const float* out_b1   = (const float*)d_in[19];
    const float* out_w2   = (const float*)d_in[20];
    const float* out_b2   = (const float*)d_in[21];
    float* outp = (float*)d_out;

    const int E1 = BGR * N1C * KNN * 2 + BGR * N1C; // 344064
    char* ws = (char*)d_ws;
    size_t o = 0;
    auto take = [&](size_t bytes) -> char* {
        char* p = ws + o;
        o += (bytes + 255) & ~(size_t)255;
        return p;
    };
    ushortT* xlrb = (ushortT*)take((size_t)16384 * 768 * 2);
    ushortT* hbf  = (ushortT*)take((size_t)16384 * 128 * 2);
    ushortT* wbt4 = (ushortT*)take((size_t)4 * 768 * 128 * 2);
    float* h0     = (float*)take((size_t)32768 * 128 * 4);
    float* h1a    = (float*)take((size_t)16384 * 128 * 4);
    float* h1b    = (float*)take((size_t)16384 * 128 * 4);
    float* h2a    = (float*)take((size_t)8192 * 128 * 4);
    float* h2b    = (float*)take((size_t)8192 * 128 * 4);
    float* ews    = (float*)take((size_t)E1 * 4);
    float* pos1   = (float*)take((size_t)16384 * 3 * 4);
    float* pos2   = (float*)take((size_t)8192 * 3 * 4);
    float* plog   = (float*)take((size_t)32768 * 4);
    float* vals   = (float*)take((size_t)16384 * 4);
    float* apart  = (float*)take((size_t)16 * 32 * 128 * 4);
    float* catb   = (float*)take((size_t)12288 * 4);
    float* stats  = (float*)take((size_t)256 * 4);
    float* parts  = (float*)take((size_t)128 * 256 * 4);
    int* knnb     = (int*)take((size_t)163840 * 4);
    int* permb    = (int*)take((size_t)16384 * 4);
    int* degb     = (int*)take((size_t)16385 * 4);
    int* offb     = (int*)take((size_t)16385 * 4);
    int* curb     = (int*)take((size_t)16384 * 4);
    int* eidsb    = (int*)take((size_t)E1 * 4);
    int* dstsb    = (int*)take((size_t)E1 * 4);
    int* srcsb    = (int*)take((size_t)E1 * 4);

    // run_bn with optional fused row-dot (gw/gbp -> plog)
    auto run_bn = [&](const float* in, float* out2, ushortT* bf, int rows, int layer,
                      const float* gw, const float* gbp) {
        colstats_k<<<128, 256, 0, stream>>>(in, rows, parts);
        colreduce_k<<<1, 256, 0, stream>>>(parts, stats);
        bn_apply_k<<<(rows * 128) / 256, 256, 0, stream>>>(in, out2, bf, stats,
                                                           bn_g + layer * H, bn_b + layer * H,
                                                           gw, gbp, plog, rows);
    };
    // pool: plog already filled by producer (bn_apply fusion)
    auto run_pool = [&](const float* hsrc, const float* possrc, float* hdst, float* posdst,
                        int n, int keep, const float* gw, const float* gbp) {
        pool_rank_k<<<BGR * (n / 64), 256, 0, stream>>>(plog, n, keep, permb, vals);
        pool_gather_k<<<(BGR * keep * 128) / 256, 256, 0, stream>>>(hsrc, possrc, permb, vals,
                                                                    hdst, hbf, posdst,
                                                                    gw, gbp, plog, BGR * keep);
    };
    // readout: plog already filled by producer
    auto run_readout = [&](const float* hsrc, int n, int g, int catoff) {
        int chunks = n / 64;
        att_partial_k<<<BGR * chunks, 256, 0, stream>>>(hsrc, plog, n, apart);
        ro_gemm_k<<<BGR, 256, 0, stream>>>(apart, chunks, ro_w + (size_t)g * H * 256, ro_b + g * 256, catb, catoff);
    };
    auto build_graph = [&](const float* posb, int n, int st) {
        int NB = BGR * n, E = NB * KNN * 2 + NB;
        hipMemsetAsync(degb, 0, (size_t)NB * 4, stream);
        knn_k<<<NB / 4, 256, 0, stream>>>(posb, n, knnb, degb);
        scan_k<<<1, 1024, 0, stream>>>(degb, offb, curb, NB);
        fill_eids_k<<<E / 256, 256, 0, stream>>>(knnb, NB, E, curb, eidsb, dstsb);
        rank_gather_k<<<E / 256, 256, 0, stream>>>(eidsb, dstsb, offb, knnb, posb, NB, E,
                                                   em_w1 + st * 32, em_b1 + st * 32,
                                                   em_w2 + st * 32, em_b2 + st, srcsb, ews);
    };
    auto run_gat = [&](const float* hin, float* hout, int NB, int n, int layer) {
        gemm_mfma_k<<<(NB / 128) * 6, 256, 0, stream>>>(hbf, wbt4 + (size_t)layer * 98304, xlrb, NB);
        int nslots = NB / 4;
        int grid = nslots < 2048 ? nslots : 2048;
        gat_fused_k<<<grid, 256, 0, stream>>>(hin, xlrb, offb, srcsb, ews, NB, n,
                                              conv_We + layer * 384, conv_att + layer * 384,
                                              conv_bias + layer * H, hout);
    };

    wcvt_all_k<<<1536, 256, 0, stream>>>(conv_Wl, conv_Wr, wbt4);
    // BN0 fused with pool_w[0] dot -> plog
    run_bn(x, h0, nullptr, BGR * N0C, 0, pool_w, nullptr);
    // pool1 (uses plog); gather fused with gate_w[0] dot -> plog for r1
    run_pool(h0, pos, h1a, pos1, N0C, N1C, gate_w, gate_b);
    run_readout(h1a, N1C, 0, 512);
    build_graph(pos1, N1C, 0);
    // hbf for layer0 GEMM comes from pool_gather's bf16 output (h1a)
    run_gat(h1a, h1b, BGR * N1C, N1C, 0);
    run_bn(h1b, h1a, hbf, BGR * N1C, 1, nullptr, nullptr);
    run_gat(h1a, h1b, BGR * N1C, N1C, 1);
    // BN2 fused with pool_w[1] dot -> plog
    run_bn(h1b, h1a, nullptr, BGR * N1C, 2, pool_w + H, nullptr);
    run_pool(h1a, pos1, h2a, pos2, N1C, N2C, gate_w + H, gate_b + 1);
    run_readout(h2a, N2C, 1, 256);
    build_graph(pos2, N2C, 1);
    run_gat(h2a, h2b, BGR * N2C, N2C, 2);
    run_bn(h2b, h2a, hbf, BGR * N2C, 3, nullptr, nullptr);
    run_gat(h2a, h2b, BGR * N2C, N2C, 3);
    // BN4 fused with gate_w[2] dot -> plog for r3
    run_bn(h2b, h2a, nullptr, BGR * N2C, 4, gate_w + 2 * H, gate_b + 2);
    run_readout(h2a, N2C, 2, 0);
    head_k<<<BGR, 128, 0, stream>>>(catb, out_w1, out_b1, out_w2, out_b2, outp);
}

// Round 17
// 611.251 us; speedup vs baseline: 1.1994x; 1.0185x over previous
//
#include <hip/hip_runtime.h>
#include <math.h>

#define H 128
#define NHEADS 3
#define BGR 16
#define N0C 2048
#define N1C 1024
#define N2C 512
#define KNN 10
#define EPSV 1e-5f

typedef unsigned short ushortT;
typedef __attribute__((ext_vector_type(8))) short short8;
typedef __attribute__((ext_vector_type(4))) short s16x4;
typedef __attribute__((ext_vector_type(4))) float f32x4;
typedef __attribute__((ext_vector_type(2))) float f32x2;

static __device__ __forceinline__ unsigned short f2bf(float f) {
    unsigned u = __float_as_uint(f);
    unsigned r = (u + 0x7FFF + ((u >> 16) & 1)) >> 16;
    return (unsigned short)r;
}
static __device__ __forceinline__ float bf2f(unsigned short s) {
    return __uint_as_float(((unsigned)s) << 16);
}

// ---- DPP helpers (VALU-pipe cross-lane; ctrl: 0xB1=quad xor1, 0x4E=quad xor2,
//      0x124=row_ror:4, 0x128=row_ror:8). All source lanes valid in our uses. ----
template<int CTRL>
static __device__ __forceinline__ float dpp_addf(float x) {
    int y = __builtin_amdgcn_update_dpp(0, __float_as_int(x), CTRL, 0xF, 0xF, true);
    return x + __int_as_float(y);
}
template<int CTRL>
static __device__ __forceinline__ float dpp_movf(float x) {
    return __int_as_float(__builtin_amdgcn_update_dpp(0, __float_as_int(x), CTRL, 0xF, 0xF, true));
}
template<int CTRL>
static __device__ __forceinline__ int dpp_movi(int x) {
    return __builtin_amdgcn_update_dpp(0, x, CTRL, 0xF, 0xF, true);
}
// row(16)-wide all-reduce sum via DPP (4 VALU adds)
static __device__ __forceinline__ float dpp_rowsum(float x) {
    x = dpp_addf<0xB1>(x);
    x = dpp_addf<0x4E>(x);
    x = dpp_addf<0x124>(x);
    x = dpp_addf<0x128>(x);
    return x;
}
// one argmin combine stage via DPP rotation
template<int CTRL>
static __device__ __forceinline__ void dpp_argmin(float& v, int& i) {
    float ov = dpp_movf<CTRL>(v);
    int oi = dpp_movi<CTRL>(i);
    if (ov < v || (ov == v && oi < i)) { v = ov; i = oi; }
}

// ---------------- decode edge -> (src,dst) from knn table ----------------
static __device__ __forceinline__ int decode_src(int e, int BNK, const int* __restrict__ knn) {
    if (e < BNK) return knn[e];
    int f = e - BNK;
    if (f < BNK) return f / KNN;
    return f - BNK;
}
static __device__ __forceinline__ int decode_dst(int e, int BNK, const int* __restrict__ knn) {
    if (e < BNK) return e / KNN;
    int f = e - BNK;
    if (f < BNK) return knn[f];
    return f - BNK;
}

// ---------------- batchnorm (optionally fused row-dot -> plog) ----------------
__global__ void colstats_k(const float* __restrict__ xin, int rows, float* __restrict__ part) {
    int c = threadIdx.x & 127, rr = threadIdx.x >> 7;
    float s = 0.f, q = 0.f;
    for (int r = blockIdx.x * 2 + rr; r < rows; r += 256) {
        float v = xin[(size_t)r * H + c];
        s += v; q += v * v;
    }
    __shared__ float ls[256], lq[256];
    ls[threadIdx.x] = s; lq[threadIdx.x] = q;
    __syncthreads();
    if (rr == 0) {
        part[blockIdx.x * 256 + c]       = s + ls[threadIdx.x + 128];
        part[blockIdx.x * 256 + 128 + c] = q + lq[threadIdx.x + 128];
    }
}
__global__ void colreduce_k(const float* __restrict__ part, float* __restrict__ stats) {
    int t = threadIdx.x; // 256
    float s = 0.f;
    for (int p = 0; p < 128; p++) s += part[p * 256 + t];
    stats[t] = s;
}
// block = 256 threads = 2 rows
__global__ void bn_apply_k(const float* __restrict__ xin, float* __restrict__ xout,
                           ushortT* __restrict__ bfout,
                           const float* __restrict__ stats, const float* __restrict__ g,
                           const float* __restrict__ b,
                           const float* __restrict__ gw, const float* __restrict__ gbp,
                           float* __restrict__ plog, int rows) {
    int idx = blockIdx.x * 256 + threadIdx.x;
    int t = threadIdx.x;
    int c = idx & 127;
    float mean = stats[c] / rows;
    float var = stats[128 + c] / rows - mean * mean;
    float v = (xin[idx] - mean) * rsqrtf(var + EPSV) * g[c] + b[c];
    xout[idx] = v;
    if (bfout) bfout[idx] = f2bf(v);
    if (gw) {
        __shared__ float red[256];
        red[t] = v * gw[c];
        __syncthreads();
        int hh = t & 127;
        for (int st = 64; st; st >>= 1) {
            if (hh < st) red[t] += red[t + st];
            __syncthreads();
        }
        if (hh == 0) plog[idx >> 7] = red[t] + (gbp ? gbp[0] : 0.f);
    }
}

// ---------------- top-k pool: rank raw logits, 4 threads per i ----------------
__global__ void pool_rank_k(const float* __restrict__ logit, int n, int keep,
                            int* __restrict__ perm, float* __restrict__ vals) {
    __shared__ float s[2048];
    __shared__ float red[256];
    int groups = n >> 6;
    int b = blockIdx.x / groups, ch = blockIdx.x % groups;
    int t = threadIdx.x; // 256
    const float* L = logit + b * n;
    float mx = -1e30f;
    for (int i = t; i < n; i += 256) { float v = L[i]; s[i] = v; mx = fmaxf(mx, v); }
    red[t] = mx; __syncthreads();
    for (int st = 128; st; st >>= 1) { if (t < st) red[t] = fmaxf(red[t], red[t + st]); __syncthreads(); }
    mx = red[0]; __syncthreads();
    float sm = 0.f;
    for (int i = t; i < n; i += 256) sm += __expf(s[i] - mx);
    red[t] = sm; __syncthreads();
    for (int st = 128; st; st >>= 1) { if (t < st) red[t] += red[t + st]; __syncthreads(); }
    float inv = 1.f / red[0];
    __syncthreads();
    int il = t >> 2, q = t & 3;
    int i = ch * 64 + il;
    float si = s[i];
    int cnt = 0;
    const float4* s4 = (const float4*)s;
    int K4 = n >> 4;
    #pragma unroll 4
    for (int kk = 0; kk < K4; kk++) {
        int jj = kk * 4 + q;
        float4 v = s4[jj];
        int jb = jj * 4;
        cnt += (v.x > si) || (v.x == si && (jb + 0) < i);
        cnt += (v.y > si) || (v.y == si && (jb + 1) < i);
        cnt += (v.z > si) || (v.z == si && (jb + 2) < i);
        cnt += (v.w > si) || (v.w == si && (jb + 3) < i);
    }
    cnt += __shfl_xor(cnt, 1);
    cnt += __shfl_xor(cnt, 2);
    if (q == 0 && cnt < keep) { perm[b * keep + cnt] = b * n + i; vals[b * keep + cnt] = __expf(si - mx) * inv; }
}
// gathers pooled rows; optionally fused gate-dot -> plog (block = 2 rows)
__global__ void pool_gather_k(const float* __restrict__ hsrc, const float* __restrict__ possrc,
                              const int* __restrict__ perm, const float* __restrict__ vals,
                              float* __restrict__ hd, ushortT* __restrict__ bfout,
                              float* __restrict__ posd,
                              const float* __restrict__ gw, const float* __restrict__ gbp,
                              float* __restrict__ plog, int rows) {
    int idx = blockIdx.x * 256 + threadIdx.x;
    int t = threadIdx.x;
    int r = idx >> 7, c = idx & 127;
    int p = perm[r];
    float v = hsrc[(size_t)p * H + c] * vals[r];
    hd[idx] = v;
    bfout[idx] = f2bf(v);
    if (c < 3) posd[r * 3 + c] = possrc[p * 3 + c];
    if (gw) {
        __shared__ float red[256];
        red[t] = v * gw[c];
        __syncthreads();
        int hh = t & 127;
        for (int st = 64; st; st >>= 1) {
            if (hh < st) red[t] += red[t + st];
            __syncthreads();
        }
        if (hh == 0) plog[r] = red[t] + (gbp ? gbp[0] : 0.f);
    }
}

// ---------------- attention readout: softmax fused into weighted column sum ----------------
__global__ void att_partial_k(const float* __restrict__ hsrc, const float* __restrict__ plog,
                              int n, float* __restrict__ part) {
    __shared__ float s[1024];
    __shared__ float red[256];
    int chunks = n >> 6;
    int b = blockIdx.x / chunks, ch = blockIdx.x % chunks;
    int t = threadIdx.x;
    const float* L = plog + b * n;
    float mx = -1e30f;
    for (int i = t; i < n; i += 256) { float v = L[i]; s[i] = v; mx = fmaxf(mx, v); }
    red[t] = mx; __syncthreads();
    for (int st = 128; st; st >>= 1) { if (t < st) red[t] = fmaxf(red[t], red[t + st]); __syncthreads(); }
    mx = red[0]; __syncthreads();
    float sm = 0.f;
    for (int i = t; i < n; i += 256) sm += __expf(s[i] - mx);
    red[t] = sm; __syncthreads();
    for (int st = 128; st; st >>= 1) { if (t < st) red[t] += red[t + st]; __syncthreads(); }
    float inv = 1.f / red[0];
    __syncthreads();
    int c = t & 127, rg = t >> 7;
    int r0 = ch * 64;
    float acc = 0.f;
    for (int i = rg; i < 64; i += 2) {
        int r = r0 + i;
        acc += __expf(s[r] - mx) * inv * hsrc[((size_t)b * n + r) * H + c];
    }
    red[t] = acc; __syncthreads();
    if (rg == 0) part[((size_t)b * chunks + ch) * H + c] = red[c] + red[128 + c];
}
// fused chunk-reduce + [1,128]@[128,256] readout GEMM
__global__ void ro_gemm_k(const float* __restrict__ part, int chunks,
                          const float* __restrict__ w, const float* __restrict__ bias,
                          float* __restrict__ catp, int coff) {
    int b = blockIdx.x, d = threadIdx.x; // 256
    __shared__ float hb[128];
    if (d < 128) {
        float s2 = 0.f;
        for (int ch = 0; ch < chunks; ch++) s2 += part[((size_t)b * chunks + ch) * H + d];
        hb[d] = s2;
    }
    __syncthreads();
    float acc = bias[d];
    for (int c = 0; c < 128; c++) acc += hb[c] * w[c * 256 + d];
    catp[b * 768 + coff + d] = acc;
}

// ---------------- kNN (k=10) — register-resident, 4-chain argmin, DPP reduce ----------------
__global__ void knn_k(const float* __restrict__ pos, int n, int* __restrict__ knn,
                      int* __restrict__ deg) {
    int wv = blockIdx.x * 4 + (threadIdx.x >> 6);
    int lane = threadIdx.x & 63;
    int b = wv / n;
    const float* pb = pos + (size_t)b * n * 3;
    float px = pos[(size_t)wv * 3], py = pos[(size_t)wv * 3 + 1], pz = pos[(size_t)wv * 3 + 2];
    int T = n >> 6;
    float d2v[16];
    #pragma unroll
    for (int t = 0; t < 16; t++) {
        if (t < T) {
            int j = lane + (t << 6);
            float dx = pb[j * 3] - px, dy = pb[j * 3 + 1] - py, dz = pb[j * 3 + 2] - pz;
            d2v[t] = dx * dx + dy * dy + dz * dz;
        } else {
            d2v[t] = 1e30f;
        }
    }
    for (int r = 0; r < KNN; r++) {
        float bv0 = d2v[0];  int bt0 = 0;
        float bv1 = d2v[4];  int bt1 = 4;
        float bv2 = d2v[8];  int bt2 = 8;
        float bv3 = d2v[12]; int bt3 = 12;
        #pragma unroll
        for (int t = 1; t < 4; t++) {
            if (d2v[t]      < bv0) { bv0 = d2v[t];      bt0 = t; }
            if (d2v[4 + t]  < bv1) { bv1 = d2v[4 + t];  bt1 = 4 + t; }
            if (d2v[8 + t]  < bv2) { bv2 = d2v[8 + t];  bt2 = 8 + t; }
            if (d2v[12 + t] < bv3) { bv3 = d2v[12 + t]; bt3 = 12 + t; }
        }
        if (bv1 < bv0) { bv0 = bv1; bt0 = bt1; }
        if (bv3 < bv2) { bv2 = bv3; bt2 = bt3; }
        if (bv2 < bv0) { bv0 = bv2; bt0 = bt2; }
        float bv = bv0;
        int bidx = lane + (bt0 << 6);
        // row(16) argmin via DPP rotations (VALU pipe), then cross-row/half via shfl
        dpp_argmin<0xB1>(bv, bidx);
        dpp_argmin<0x4E>(bv, bidx);
        dpp_argmin<0x124>(bv, bidx);
        dpp_argmin<0x128>(bv, bidx);
        {
            float ov = __shfl_xor(bv, 16);
            int oi = __shfl_xor(bidx, 16);
            if (ov < bv || (ov == bv && oi < bidx)) { bv = ov; bidx = oi; }
            ov = __shfl_xor(bv, 32);
            oi = __shfl_xor(bidx, 32);
            if (ov < bv || (ov == bv && oi < bidx)) { bv = ov; bidx = oi; }
        }
        bool win = (bidx & 63) == lane;
        int wt = bidx >> 6;
        #pragma unroll
        for (int t = 0; t < 16; t++)
            if (win && t == wt) d2v[t] = 1e30f;
        if (lane == 0) {
            knn[(size_t)wv * KNN + r] = b * n + bidx;
            atomicAdd(&deg[b * n + bidx], 1);
        }
    }
}

// ---------------- CSR by dst ----------------
__global__ __launch_bounds__(1024) void scan_k(const int* __restrict__ deg, int* __restrict__ off,
                                               int* __restrict__ cur, int NB) {
    __shared__ int part[1024];
    int t = threadIdx.x;
    int per = NB >> 10;
    int base = t * per;
    int s = 0;
    for (int i = 0; i < per; i++) s += deg[base + i] + KNN + 1;
    part[t] = s; __syncthreads();
    for (int d = 1; d < 1024; d <<= 1) {
        int v = (t >= d) ? part[t - d] : 0;
        __syncthreads();
        part[t] += v;
        __syncthreads();
    }
    int prefix = (t > 0) ? part[t - 1] : 0;
    for (int i = 0; i < per; i++) {
        off[base + i] = prefix; cur[base + i] = prefix; prefix += deg[base + i] + KNN + 1;
    }
    if (t == 1023) off[NB] = part[1023];
}
__global__ void fill_eids_k(const int* __restrict__ knn, int NB, int E,
                            int* __restrict__ cur, int* __restrict__ eids,
                            int* __restrict__ dsts) {
    int e = blockIdx.x * 256 + threadIdx.x;
    if (e >= E) return;
    int dst = decode_dst(e, NB * KNN, knn);
    int p = atomicAdd(&cur[dst], 1);
    eids[p] = e;
    dsts[p] = dst;
}
// per slot: rank by edge id within segment (deterministic), inline edge-MLP, write src/ew sorted
__global__ void rank_gather_k(const int* __restrict__ eids, const int* __restrict__ dsts,
                              const int* __restrict__ off, const int* __restrict__ knn,
                              const float* __restrict__ pos, int NB, int E,
                              const float* __restrict__ w1, const float* __restrict__ b1,
                              const float* __restrict__ w2, const float* __restrict__ b2,
                              int* __restrict__ srcs, float* __restrict__ ews) {
    int o = blockIdx.x * 256 + threadIdx.x;
    if (o >= E) return;
    int e = eids[o];
    int d = dsts[o];
    int o0 = off[d], o1 = off[d + 1];
    int rank = 0;
    for (int q = o0; q < o1; q++) rank += (eids[q] < e);
    int src = decode_src(e, NB * KNN, knn);
    float dx = pos[src * 3] - pos[d * 3];
    float dy = pos[src * 3 + 1] - pos[d * 3 + 1];
    float dz = pos[src * 3 + 2] - pos[d * 3 + 2];
    float d2 = dx * dx + dy * dy + dz * dz;
    float dd = d2 > 0.f ? sqrtf(d2) : 0.f;
    float acc = b2[0];
    #pragma unroll
    for (int k = 0; k < 32; k++) {
        float hh = fmaxf(dd * w1[k] + b1[k], 0.f);
        acc += hh * w2[k];
    }
    srcs[o0 + rank] = src;
    ews[o0 + rank] = fmaxf(acc, 0.f);
}

// pack all 4 layers W^T bf16: BT[layer][n][k]
__global__ void wcvt_all_k(const float* __restrict__ Wl, const float* __restrict__ Wr,
                           ushortT* __restrict__ BT) {
    int i = blockIdx.x * 256 + threadIdx.x;
    if (i >= 4 * 128 * 768) return;
    int layer = i / 98304, rem = i % 98304;
    int k = rem / 768, n = rem % 768;
    const float* W = (n < 384) ? (Wl + (size_t)layer * 128 * 384) : (Wr + (size_t)layer * 128 * 384);
    int nn = (n < 384) ? n : n - 384;
    BT[(size_t)layer * 98304 + (size_t)n * 128 + k] = f2bf(W[k * 384 + nn]);
}

// ---------------- MFMA bf16 GEMM: C[M,768] = A[M,128] @ W  (BT = W^T bf16) ----------------
__global__ __launch_bounds__(256) void gemm_mfma_k(const ushortT* __restrict__ A,
                                                   const ushortT* __restrict__ BT,
                                                   ushortT* __restrict__ C, int M) {
    __shared__ ushortT As[128 * 128];
    __shared__ ushortT Bs[128 * 128];
    int nb = blockIdx.x % 6, mb = blockIdx.x / 6;
    int row0 = mb * 128, col0 = nb * 128;
    int tid = threadIdx.x;
    #pragma unroll
    for (int it = 0; it < 8; it++) {
        int idx = tid + it * 256;          // 16B units
        int row = idx >> 4, seg = idx & 15;
        int byte = (row * 256 + seg * 16) ^ ((row & 7) << 4);
        *(float4*)((char*)As + byte) =
            *(const float4*)((const char*)(A + (size_t)(row0 + row) * 128) + seg * 16);
        *(float4*)((char*)Bs + byte) =
            *(const float4*)((const char*)(BT + (size_t)(col0 + row) * 128) + seg * 16);
    }
    __syncthreads();
    int wave = tid >> 6, lane = tid & 63;
    int wr = wave >> 1, wc = wave & 1;
    f32x4 acc[4][4] = {};
    int lrow = lane & 15;
    int lkb = (lane >> 4) * 16;
    #pragma unroll
    for (int ks = 0; ks < 4; ks++) {
        short8 af[4], bfr[4];
        #pragma unroll
        for (int m = 0; m < 4; m++) {
            int row = wr * 64 + m * 16 + lrow;
            int byte = (row * 256 + ks * 64 + lkb) ^ ((row & 7) << 4);
            af[m] = *(short8*)((char*)As + byte);
        }
        #pragma unroll
        for (int n = 0; n < 4; n++) {
            int col = wc * 64 + n * 16 + lrow;
            int byte = (col * 256 + ks * 64 + lkb) ^ ((col & 7) << 4);
            bfr[n] = *(short8*)((char*)Bs + byte);
        }
        #pragma unroll
        for (int m = 0; m < 4; m++)
            #pragma unroll
            for (int n = 0; n < 4; n++)
                acc[m][n] = __builtin_amdgcn_mfma_f32_16x16x32_bf16(af[m], bfr[n], acc[m][n], 0, 0, 0);
    }
    #pragma unroll
    for (int m = 0; m < 4; m++)
        #pragma unroll
        for (int n = 0; n < 4; n++) {
            int r0 = row0 + wr * 64 + m * 16 + (lane >> 4) * 4;
            int c = col0 + wc * 64 + n * 16 + (lane & 15);
            #pragma unroll
            for (int j = 0; j < 4; j++)
                C[(size_t)(r0 + j) * 768 + c] = f2bf(acc[m][n][j]);
        }
}

// ---------------- fused GAT: persistent grid, half-wave per edge, DPP reduce ----------------
__global__ __launch_bounds__(256) void gat_fused_k(
        const float* __restrict__ hin, const ushortT* __restrict__ xlr,
        const int* __restrict__ off, const int* __restrict__ srcs,
        const float* __restrict__ ews, int NB, int n,
        const float* __restrict__ We, const float* __restrict__ att,
        const float* __restrict__ bias, float* __restrict__ hout) {
    int bpg = n >> 2;
    int nslots = NB >> 2;
    int lane = threadIdx.x & 63;
    int l = lane & 31, half = lane >> 5;
    int wid = threadIdx.x >> 6;
    for (int sb = blockIdx.x; sb < nslots; sb += 2048) {
        int xcd = sb & 7, slot = sb >> 3;
        int gid = xcd + 8 * (slot / bpg);
        int node = gid * n + (slot % bpg) * 4 + wid;
        if (node >= NB) continue;
        f32x2 weP[3][2], atP[3][2], xrP[3][2];
        const ushortT* xrp = xlr + (size_t)node * 768 + 384;
        #pragma unroll
        for (int j = 0; j < 3; j++) {
            float4 wv = *(const float4*)(We + j * 128 + l * 4);
            float4 av = *(const float4*)(att + j * 128 + l * 4);
            uint2 u = *(const uint2*)(xrp + j * 128 + l * 4);
            weP[j][0] = f32x2{wv.x, wv.y}; weP[j][1] = f32x2{wv.z, wv.w};
            atP[j][0] = f32x2{av.x, av.y}; atP[j][1] = f32x2{av.z, av.w};
            xrP[j][0] = f32x2{__uint_as_float(u.x << 16), __uint_as_float(u.x & 0xFFFF0000u)};
            xrP[j][1] = f32x2{__uint_as_float(u.y << 16), __uint_as_float(u.y & 0xFFFF0000u)};
        }
        float d[3] = {0.f, 0.f, 0.f};
        f32x2 acc[3][2] = {};
        int o0 = off[node], o1 = off[node + 1];
        int o = o0 + half;
        int src = 0; float w = 0.f;
        if (o < o1) { src = srcs[o]; w = ews[o]; }
        while (o < o1) {
            int on = o + 2;
            int src_n = 0; float w_n = 0.f;
            if (on < o1) { src_n = srcs[on]; w_n = ews[on]; }
            const ushortT* pl = xlr + (size_t)src * 768;
            float p[3];
            f32x2 xv[3][2];
            #pragma unroll
            for (int j = 0; j < 3; j++) {
                uint2 u = *(const uint2*)(pl + j * 128 + l * 4);
                f32x2 x0 = {__uint_as_float(u.x << 16), __uint_as_float(u.x & 0xFFFF0000u)};
                f32x2 x1 = {__uint_as_float(u.y << 16), __uint_as_float(u.y & 0xFFFF0000u)};
                xv[j][0] = x0; xv[j][1] = x1;
                f32x2 z0 = x0 + (xrP[j][0] + w * weP[j][0]);
                f32x2 z1 = x1 + (xrP[j][1] + w * weP[j][1]);
                z0 = __builtin_elementwise_max(z0, z0 * 0.2f);
                z1 = __builtin_elementwise_max(z1, z1 * 0.2f);
                f32x2 pv = z0 * atP[j][0] + z1 * atP[j][1];
                p[j] = pv.x + pv.y;
            }
            // row(16) all-reduce on VALU pipe, then one DS op across rows of the half
            #pragma unroll
            for (int j = 0; j < 3; j++) {
                p[j] = dpp_rowsum(p[j]);
                p[j] += __shfl_xor(p[j], 16);
            }
            #pragma unroll
            for (int j = 0; j < 3; j++) {
                float e = __expf(fminf(p[j], 60.f));
                d[j] += e;
                acc[j][0] += e * xv[j][0];
                acc[j][1] += e * xv[j][1];
            }
            o = on; src = src_n; w = w_n;
        }
        #pragma unroll
        for (int j = 0; j < 3; j++) {
            d[j] += __shfl_xor(d[j], 32);
            #pragma unroll
            for (int pr = 0; pr < 2; pr++) {
                acc[j][pr].x += __shfl_xor(acc[j][pr].x, 32);
                acc[j][pr].y += __shfl_xor(acc[j][pr].y, 32);
            }
        }
        if (half == 0) {
            float4 bv = *(const float4*)(bias + l * 4);
            float4 hv = *(const float4*)(hin + (size_t)node * H + l * 4);
            float i0 = 1.f / d[0], i1 = 1.f / d[1], i2 = 1.f / d[2];
            float av[4] = {acc[0][0].x, acc[0][0].y, acc[0][1].x, acc[0][1].y};
            float bv1[4] = {acc[1][0].x, acc[1][0].y, acc[1][1].x, acc[1][1].y};
            float cv[4] = {acc[2][0].x, acc[2][0].y, acc[2][1].x, acc[2][1].y};
            float bb[4] = {bv.x, bv.y, bv.z, bv.w};
            float hh[4] = {hv.x, hv.y, hv.z, hv.w};
            float ob[4];
            #pragma unroll
            for (int q = 0; q < 4; q++) {
                float g = (av[q] * i0 + bv1[q] * i1 + cv[q] * i2) * (1.f / 3.f) + bb[q];
                float xa = hh[q] + g;
                ob[q] = xa / (1.f + __expf(-xa));
            }
            *(float4*)(hout + (size_t)node * H + l * 4) = make_float4(ob[0], ob[1], ob[2], ob[3]);
        }
    }
}

// ---------------- output head ----------------
__global__ void head_k(const float* __restrict__ cat, const float* __restrict__ W1,
                       const float* __restrict__ b1, const float* __restrict__ W2,
                       const float* __restrict__ b2, float* __restrict__ outp) {
    int b = blockIdx.x, d = threadIdx.x; // 128
    __shared__ float cs[768];
    __shared__ float o1[128];
    for (int i = d; i < 768; i += 128) cs[i] = cat[b * 768 + i];
    __syncthreads();
    float s = b1[d];
    for (int c = 0; c < 768; c++) s += cs[c] * W1[c * 128 + d];
    o1[d] = fmaxf(s, 0.f);
    __syncthreads();
    float s2 = b2[d];
    for (int c = 0; c < 128; c++) s2 += o1[c] * W2[c * 128 + d];
    outp[b * 128 + d] = s2;
}

// ---------------- driver ----------------
extern "C" void kernel_launch(void* const* d_in, const int* in_sizes, int n_in,
                              void* d_out, int out_size, void* d_ws, size_t ws_size,
                              hipStream_t stream) {
    (void)in_sizes; (void)n_in; (void)out_size; (void)ws_size;
    const float* x        = (const float*)d_in[0];
    const float* pos      = (const float*)d_in[1];
    const float* bn_g     = (const float*)d_in[2];
    const float* bn_b     = (const float*)d_in[3];
    const float* conv_Wl  = (const float*)d_in[4];
    const float* conv_Wr  = (const float*)d_in[5];
    const float* conv_We  = (const float*)d_in[6];
    const float* conv_att = (const float*)d_in[7];
    const float* conv_bias= (const float*)d_in[8];
    const float* pool_w   = (const float*)d_in[9];
    const float* gate_w   = (const float*)d_in[10];
    const float* gate_b   = (const float*)d_in[11];
    const float* ro_w     = (const float*)d_in[12];
    const float* ro_b     = (const float*)d_in[13];
    const float* em_w1    = (const float*)d_in[14];
    const float* em_b1    = (const float*)d_in[15];
    const float* em_w2    = (const float*)d_in[16];
    const float* em_b2    = (const float*)d_in[17];
    const float* out_w1   = (const float*)d_in[18];
    const float* out_b1   = (const float*)d_in[19];
    const float* out_w2   = (const float*)d_in[20];
    const float* out_b2   = (const float*)d_in[21];
    float* outp = (float*)d_out;

    const int E1 = BGR * N1C * KNN * 2 + BGR * N1C; // 344064
    char* ws = (char*)d_ws;
    size_t o = 0;
    auto take = [&](size_t bytes) -> char* {
        char* p = ws + o;
        o += (bytes + 255) & ~(size_t)255;
        return p;
    };
    ushortT* xlrb = (ushortT*)take((size_t)16384 * 768 * 2);
    ushortT* hbf  = (ushortT*)take((size_t)16384 * 128 * 2);
    ushortT* wbt4 = (ushortT*)take((size_t)4 * 768 * 128 * 2);
    float* h0     = (float*)take((size_t)32768 * 128 * 4);
    float* h1a    = (float*)take((size_t)16384 * 128 * 4);
    float* h1b    = (float*)take((size_t)16384 * 128 * 4);
    float* h2a    = (float*)take((size_t)8192 * 128 * 4);
    float* h2b    = (float*)take((size_t)8192 * 128 * 4);
    float* ews    = (float*)take((size_t)E1 * 4);
    float* pos1   = (float*)take((size_t)16384 * 3 * 4);
    float* pos2   = (float*)take((size_t)8192 * 3 * 4);
    float* plog   = (float*)take((size_t)32768 * 4);
    float* vals   = (float*)take((size_t)16384 * 4);
    float* apart  = (float*)take((size_t)16 * 32 * 128 * 4);
    float* catb   = (float*)take((size_t)12288 * 4);
    float* stats  = (float*)take((size_t)256 * 4);
    float* parts  = (float*)take((size_t)128 * 256 * 4);
    int* knnb     = (int*)take((size_t)163840 * 4);
    int* permb    = (int*)take((size_t)16384 * 4);
    int* degb     = (int*)take((size_t)16385 * 4);
    int* offb     = (int*)take((size_t)16385 * 4);
    int* curb     = (int*)take((size_t)16384 * 4);
    int* eidsb    = (int*)take((size_t)E1 * 4);
    int* dstsb    = (int*)take((size_t)E1 * 4);
    int* srcsb    = (int*)take((size_t)E1 * 4);

    auto run_bn = [&](const float* in, float* out2, ushortT* bf, int rows, int layer,
                      const float* gw, const float* gbp) {
        colstats_k<<<128, 256, 0, stream>>>(in, rows, parts);
        colreduce_k<<<1, 256, 0, stream>>>(parts, stats);
        bn_apply_k<<<(rows * 128) / 256, 256, 0, stream>>>(in, out2, bf, stats,
                                                           bn_g + layer * H, bn_b + layer * H,
                                                           gw, gbp, plog, rows);
    };
    auto run_pool = [&](const float* hsrc, const float* possrc, float* hdst, float* posdst,
                        int n, int keep, const float* gw, const float* gbp) {
        pool_rank_k<<<BGR * (n / 64), 256, 0, stream>>>(plog, n, keep, permb, vals);
        pool_gather_k<<<(BGR * keep * 128) / 256, 256, 0, stream>>>(hsrc, possrc, permb, vals,
                                                                    hdst, hbf, posdst,
                                                                    gw, gbp, plog, BGR * keep);
    };
    auto run_readout = [&](const float* hsrc, int n, int g, int catoff) {
        int chunks = n / 64;
        att_partial_k<<<BGR * chunks, 256, 0, stream>>>(hsrc, plog, n, apart);
        ro_gemm_k<<<BGR, 256, 0, stream>>>(apart, chunks, ro_w + (size_t)g * H * 256, ro_b + g * 256, catb, catoff);
    };
    auto build_graph = [&](const float* posb, int n, int st) {
        int NB = BGR * n, E = NB * KNN * 2 + NB;
        hipMemsetAsync(degb, 0, (size_t)NB * 4, stream);
        knn_k<<<NB / 4, 256, 0, stream>>>(posb, n, knnb, degb);
        scan_k<<<1, 1024, 0, stream>>>(degb, offb, curb, NB);
        fill_eids_k<<<E / 256, 256, 0, stream>>>(knnb, NB, E, curb, eidsb, dstsb);
        rank_gather_k<<<E / 256, 256, 0, stream>>>(eidsb, dstsb, offb, knnb, posb, NB, E,
                                                   em_w1 + st * 32, em_b1 + st * 32,
                                                   em_w2 + st * 32, em_b2 + st, srcsb, ews);
    };
    auto run_gat = [&](const float* hin, float* hout, int NB, int n, int layer) {
        gemm_mfma_k<<<(NB / 128) * 6, 256, 0, stream>>>(hbf, wbt4 + (size_t)layer * 98304, xlrb, NB);
        int nslots = NB / 4;
        int grid = nslots < 2048 ? nslots : 2048;
        gat_fused_k<<<grid, 256, 0, stream>>>(hin, xlrb, offb, srcsb, ews, NB, n,
                                              conv_We + layer * 384, conv_att + layer * 384,
                                              conv_bias + layer * H, hout);
    };

    wcvt_all_k<<<1536, 256, 0, stream>>>(conv_Wl, conv_Wr, wbt4);
    run_bn(x, h0, nullptr, BGR * N0C, 0, pool_w, nullptr);
    run_pool(h0, pos, h1a, pos1, N0C, N1C, gate_w, gate_b);
    run_readout(h1a, N1C, 0, 512);
    build_graph(pos1, N1C, 0);
    run_gat(h1a, h1b, BGR * N1C, N1C, 0);
    run_bn(h1b, h1a, hbf, BGR * N1C, 1, nullptr, nullptr);
    run_gat(h1a, h1b, BGR * N1C, N1C, 1);
    run_bn(h1b, h1a, nullptr, BGR * N1C, 2, pool_w + H, nullptr);
    run_pool(h1a, pos1, h2a, pos2, N1C, N2C, gate_w + H, gate_b + 1);
    run_readout(h2a, N2C, 1, 256);
    build_graph(pos2, N2C, 1);
    run_gat(h2a, h2b, BGR * N2C, N2C, 2);
    run_bn(h2b, h2a, hbf, BGR * N2C, 3, nullptr, nullptr);
    run_gat(h2a, h2b, BGR * N2C, N2C, 3);
    run_bn(h2b, h2a, nullptr, BGR * N2C, 4, gate_w + 2 * H, gate_b + 2);
    run_readout(h2a, N2C, 2, 0);
    head_k<<<BGR, 128, 0, stream>>>(catb, out_w1, out_b1, out_w2, out_b2, outp);
}

// Round 18
// 602.520 us; speedup vs baseline: 1.2167x; 1.0145x over previous
//
#include <hip/hip_runtime.h>
#include <math.h>

#define H 128
#define NHEADS 3
#define BGR 16
#define N0C 2048
#define N1C 1024
#define N2C 512
#define KNN 10
#define EPSV 1e-5f
#define CS_BLOCKS 512

typedef unsigned short ushortT;
typedef __attribute__((ext_vector_type(8))) short short8;
typedef __attribute__((ext_vector_type(4))) short s16x4;
typedef __attribute__((ext_vector_type(4))) float f32x4;
typedef __attribute__((ext_vector_type(2))) float f32x2;

static __device__ __forceinline__ unsigned short f2bf(float f) {
    unsigned u = __float_as_uint(f);
    unsigned r = (u + 0x7FFF + ((u >> 16) & 1)) >> 16;
    return (unsigned short)r;
}
static __device__ __forceinline__ float bf2f(unsigned short s) {
    return __uint_as_float(((unsigned)s) << 16);
}

// ---- DPP helpers (VALU-pipe cross-lane) ----
template<int CTRL>
static __device__ __forceinline__ float dpp_addf(float x) {
    int y = __builtin_amdgcn_update_dpp(0, __float_as_int(x), CTRL, 0xF, 0xF, true);
    return x + __int_as_float(y);
}
template<int CTRL>
static __device__ __forceinline__ float dpp_movf(float x) {
    return __int_as_float(__builtin_amdgcn_update_dpp(0, __float_as_int(x), CTRL, 0xF, 0xF, true));
}
template<int CTRL>
static __device__ __forceinline__ int dpp_movi(int x) {
    return __builtin_amdgcn_update_dpp(0, x, CTRL, 0xF, 0xF, true);
}
static __device__ __forceinline__ float dpp_rowsum(float x) {
    x = dpp_addf<0xB1>(x);
    x = dpp_addf<0x4E>(x);
    x = dpp_addf<0x124>(x);
    x = dpp_addf<0x128>(x);
    return x;
}
template<int CTRL>
static __device__ __forceinline__ void dpp_argmin(float& v, int& i) {
    float ov = dpp_movf<CTRL>(v);
    int oi = dpp_movi<CTRL>(i);
    if (ov < v || (ov == v && oi < i)) { v = ov; i = oi; }
}

// ---------------- decode edge -> (src,dst) from knn table ----------------
static __device__ __forceinline__ int decode_src(int e, int BNK, const int* __restrict__ knn) {
    if (e < BNK) return knn[e];
    int f = e - BNK;
    if (f < BNK) return f / KNN;
    return f - BNK;
}
static __device__ __forceinline__ int decode_dst(int e, int BNK, const int* __restrict__ knn) {
    if (e < BNK) return e / KNN;
    int f = e - BNK;
    if (f < BNK) return knn[f];
    return f - BNK;
}

// ---------------- batchnorm ----------------
// grid = CS_BLOCKS blocks, 256 thr = 2 rows/iter
__global__ void colstats_k(const float* __restrict__ xin, int rows, float* __restrict__ part) {
    int c = threadIdx.x & 127, rr = threadIdx.x >> 7;
    float s = 0.f, q = 0.f;
    for (int r = blockIdx.x * 2 + rr; r < rows; r += CS_BLOCKS * 2) {
        float v = xin[(size_t)r * H + c];
        s += v; q += v * v;
    }
    __shared__ float ls[256], lq[256];
    ls[threadIdx.x] = s; lq[threadIdx.x] = q;
    __syncthreads();
    if (rr == 0) {
        part[blockIdx.x * 256 + c]       = s + ls[threadIdx.x + 128];
        part[blockIdx.x * 256 + 128 + c] = q + lq[threadIdx.x + 128];
    }
}
__global__ void colreduce_k(const float* __restrict__ part, float* __restrict__ stats) {
    int t = threadIdx.x; // 256
    float s = 0.f;
    for (int p = 0; p < CS_BLOCKS; p++) s += part[p * 256 + t];
    stats[t] = s;
}
// block = 256 threads = 2 rows
__global__ void bn_apply_k(const float* __restrict__ xin, float* __restrict__ xout,
                           ushortT* __restrict__ bfout,
                           const float* __restrict__ stats, const float* __restrict__ g,
                           const float* __restrict__ b,
                           const float* __restrict__ gw, const float* __restrict__ gbp,
                           float* __restrict__ plog, int rows) {
    int idx = blockIdx.x * 256 + threadIdx.x;
    int t = threadIdx.x;
    int c = idx & 127;
    float mean = stats[c] / rows;
    float var = stats[128 + c] / rows - mean * mean;
    float v = (xin[idx] - mean) * rsqrtf(var + EPSV) * g[c] + b[c];
    xout[idx] = v;
    if (bfout) bfout[idx] = f2bf(v);
    if (gw) {
        __shared__ float red[256];
        red[t] = v * gw[c];
        __syncthreads();
        int hh = t & 127;
        for (int st = 64; st; st >>= 1) {
            if (hh < st) red[t] += red[t + st];
            __syncthreads();
        }
        if (hh == 0) plog[idx >> 7] = red[t] + (gbp ? gbp[0] : 0.f);
    }
}

// ---------------- top-k pool: rank raw logits, 4 threads per i ----------------
__global__ void pool_rank_k(const float* __restrict__ logit, int n, int keep,
                            int* __restrict__ perm, float* __restrict__ vals) {
    __shared__ float s[2048];
    __shared__ float red[256];
    int groups = n >> 6;
    int b = blockIdx.x / groups, ch = blockIdx.x % groups;
    int t = threadIdx.x; // 256
    const float* L = logit + b * n;
    float mx = -1e30f;
    for (int i = t; i < n; i += 256) { float v = L[i]; s[i] = v; mx = fmaxf(mx, v); }
    red[t] = mx; __syncthreads();
    for (int st = 128; st; st >>= 1) { if (t < st) red[t] = fmaxf(red[t], red[t + st]); __syncthreads(); }
    mx = red[0]; __syncthreads();
    float sm = 0.f;
    for (int i = t; i < n; i += 256) sm += __expf(s[i] - mx);
    red[t] = sm; __syncthreads();
    for (int st = 128; st; st >>= 1) { if (t < st) red[t] += red[t + st]; __syncthreads(); }
    float inv = 1.f / red[0];
    __syncthreads();
    int il = t >> 2, q = t & 3;
    int i = ch * 64 + il;
    float si = s[i];
    int cnt = 0;
    const float4* s4 = (const float4*)s;
    int K4 = n >> 4;
    #pragma unroll 4
    for (int kk = 0; kk < K4; kk++) {
        int jj = kk * 4 + q;
        float4 v = s4[jj];
        int jb = jj * 4;
        cnt += (v.x > si) || (v.x == si && (jb + 0) < i);
        cnt += (v.y > si) || (v.y == si && (jb + 1) < i);
        cnt += (v.z > si) || (v.z == si && (jb + 2) < i);
        cnt += (v.w > si) || (v.w == si && (jb + 3) < i);
    }
    cnt += __shfl_xor(cnt, 1);
    cnt += __shfl_xor(cnt, 2);
    if (q == 0 && cnt < keep) { perm[b * keep + cnt] = b * n + i; vals[b * keep + cnt] = __expf(si - mx) * inv; }
}
// gathers pooled rows; optionally fused gate-dot -> plog (block = 2 rows)
__global__ void pool_gather_k(const float* __restrict__ hsrc, const float* __restrict__ possrc,
                              const int* __restrict__ perm, const float* __restrict__ vals,
                              float* __restrict__ hd, ushortT* __restrict__ bfout,
                              float* __restrict__ posd,
                              const float* __restrict__ gw, const float* __restrict__ gbp,
                              float* __restrict__ plog, int rows) {
    int idx = blockIdx.x * 256 + threadIdx.x;
    int t = threadIdx.x;
    int r = idx >> 7, c = idx & 127;
    int p = perm[r];
    float v = hsrc[(size_t)p * H + c] * vals[r];
    hd[idx] = v;
    bfout[idx] = f2bf(v);
    if (c < 3) posd[r * 3 + c] = possrc[p * 3 + c];
    if (gw) {
        __shared__ float red[256];
        red[t] = v * gw[c];
        __syncthreads();
        int hh = t & 127;
        for (int st = 64; st; st >>= 1) {
            if (hh < st) red[t] += red[t + st];
            __syncthreads();
        }
        if (hh == 0) plog[r] = red[t] + (gbp ? gbp[0] : 0.f);
    }
}

// ---------------- attention readout: softmax fused into weighted column sum ----------------
__global__ void att_partial_k(const float* __restrict__ hsrc, const float* __restrict__ plog,
                              int n, float* __restrict__ part) {
    __shared__ float s[1024];
    __shared__ float red[256];
    int chunks = n >> 6;
    int b = blockIdx.x / chunks, ch = blockIdx.x % chunks;
    int t = threadIdx.x;
    const float* L = plog + b * n;
    float mx = -1e30f;
    for (int i = t; i < n; i += 256) { float v = L[i]; s[i] = v; mx = fmaxf(mx, v); }
    red[t] = mx; __syncthreads();
    for (int st = 128; st; st >>= 1) { if (t < st) red[t] = fmaxf(red[t], red[t + st]); __syncthreads(); }
    mx = red[0]; __syncthreads();
    float sm = 0.f;
    for (int i = t; i < n; i += 256) sm += __expf(s[i] - mx);
    red[t] = sm; __syncthreads();
    for (int st = 128; st; st >>= 1) { if (t < st) red[t] += red[t + st]; __syncthreads(); }
    float inv = 1.f / red[0];
    __syncthreads();
    int c = t & 127, rg = t >> 7;
    int r0 = ch * 64;
    float acc = 0.f;
    for (int i = rg; i < 64; i += 2) {
        int r = r0 + i;
        acc += __expf(s[r] - mx) * inv * hsrc[((size_t)b * n + r) * H + c];
    }
    red[t] = acc; __syncthreads();
    if (rg == 0) part[((size_t)b * chunks + ch) * H + c] = red[c] + red[128 + c];
}
// fused chunk-reduce + [1,128]@[128,256] readout GEMM
__global__ void ro_gemm_k(const float* __restrict__ part, int chunks,
                          const float* __restrict__ w, const float* __restrict__ bias,
                          float* __restrict__ catp, int coff) {
    int b = blockIdx.x, d = threadIdx.x; // 256
    __shared__ float hb[128];
    if (d < 128) {
        float s2 = 0.f;
        for (int ch = 0; ch < chunks; ch++) s2 += part[((size_t)b * chunks + ch) * H + d];
        hb[d] = s2;
    }
    __syncthreads();
    float acc = bias[d];
    for (int c = 0; c < 128; c++) acc += hb[c] * w[c * 256 + d];
    catp[b * 768 + coff + d] = acc;
}

// ---------------- kNN (k=10) — register-resident, 4-chain argmin, DPP reduce ----------------
__global__ void knn_k(const float* __restrict__ pos, int n, int* __restrict__ knn,
                      int* __restrict__ deg) {
    int wv = blockIdx.x * 4 + (threadIdx.x >> 6);
    int lane = threadIdx.x & 63;
    int b = wv / n;
    const float* pb = pos + (size_t)b * n * 3;
    float px = pos[(size_t)wv * 3], py = pos[(size_t)wv * 3 + 1], pz = pos[(size_t)wv * 3 + 2];
    int T = n >> 6;
    float d2v[16];
    #pragma unroll
    for (int t = 0; t < 16; t++) {
        if (t < T) {
            int j = lane + (t << 6);
            float dx = pb[j * 3] - px, dy = pb[j * 3 + 1] - py, dz = pb[j * 3 + 2] - pz;
            d2v[t] = dx * dx + dy * dy + dz * dz;
        } else {
            d2v[t] = 1e30f;
        }
    }
    for (int r = 0; r < KNN; r++) {
        float bv0 = d2v[0];  int bt0 = 0;
        float bv1 = d2v[4];  int bt1 = 4;
        float bv2 = d2v[8];  int bt2 = 8;
        float bv3 = d2v[12]; int bt3 = 12;
        #pragma unroll
        for (int t = 1; t < 4; t++) {
            if (d2v[t]      < bv0) { bv0 = d2v[t];      bt0 = t; }
            if (d2v[4 + t]  < bv1) { bv1 = d2v[4 + t];  bt1 = 4 + t; }
            if (d2v[8 + t]  < bv2) { bv2 = d2v[8 + t];  bt2 = 8 + t; }
            if (d2v[12 + t] < bv3) { bv3 = d2v[12 + t]; bt3 = 12 + t; }
        }
        if (bv1 < bv0) { bv0 = bv1; bt0 = bt1; }
        if (bv3 < bv2) { bv2 = bv3; bt2 = bt3; }
        if (bv2 < bv0) { bv0 = bv2; bt0 = bt2; }
        float bv = bv0;
        int bidx = lane + (bt0 << 6);
        dpp_argmin<0xB1>(bv, bidx);
        dpp_argmin<0x4E>(bv, bidx);
        dpp_argmin<0x124>(bv, bidx);
        dpp_argmin<0x128>(bv, bidx);
        {
            float ov = __shfl_xor(bv, 16);
            int oi = __shfl_xor(bidx, 16);
            if (ov < bv || (ov == bv && oi < bidx)) { bv = ov; bidx = oi; }
            ov = __shfl_xor(bv, 32);
            oi = __shfl_xor(bidx, 32);
            if (ov < bv || (ov == bv && oi < bidx)) { bv = ov; bidx = oi; }
        }
        bool win = (bidx & 63) == lane;
        int wt = bidx >> 6;
        #pragma unroll
        for (int t = 0; t < 16; t++)
            if (win && t == wt) d2v[t] = 1e30f;
        if (lane == 0) {
            knn[(size_t)wv * KNN + r] = b * n + bidx;
            atomicAdd(&deg[b * n + bidx], 1);
        }
    }
}

// ---------------- CSR by dst ----------------
__global__ __launch_bounds__(1024) void scan_k(const int* __restrict__ deg, int* __restrict__ off,
                                               int* __restrict__ cur, int NB) {
    __shared__ int part[1024];
    int t = threadIdx.x;
    int per = NB >> 10;
    int base = t * per;
    int s = 0;
    for (int i = 0; i < per; i++) s += deg[base + i] + KNN + 1;
    part[t] = s; __syncthreads();
    for (int d = 1; d < 1024; d <<= 1) {
        int v = (t >= d) ? part[t - d] : 0;
        __syncthreads();
        part[t] += v;
        __syncthreads();
    }
    int prefix = (t > 0) ? part[t - 1] : 0;
    for (int i = 0; i < per; i++) {
        off[base + i] = prefix; cur[base + i] = prefix; prefix += deg[base + i] + KNN + 1;
    }
    if (t == 1023) off[NB] = part[1023];
}
__global__ void fill_eids_k(const int* __restrict__ knn, int NB, int E,
                            int* __restrict__ cur, int* __restrict__ eids,
                            int* __restrict__ dsts) {
    int e = blockIdx.x * 256 + threadIdx.x;
    if (e >= E) return;
    int dst = decode_dst(e, NB * KNN, knn);
    int p = atomicAdd(&cur[dst], 1);
    eids[p] = e;
    dsts[p] = dst;
}
// per slot: rank by edge id within segment, inline edge-MLP, write src/ew sorted
__global__ void rank_gather_k(const int* __restrict__ eids, const int* __restrict__ dsts,
                              const int* __restrict__ off, const int* __restrict__ knn,
                              const float* __restrict__ pos, int NB, int E,
                              const float* __restrict__ w1, const float* __restrict__ b1,
                              const float* __restrict__ w2, const float* __restrict__ b2,
                              int* __restrict__ srcs, float* __restrict__ ews) {
    int o = blockIdx.x * 256 + threadIdx.x;
    if (o >= E) return;
    int e = eids[o];
    int d = dsts[o];
    int o0 = off[d], o1 = off[d + 1];
    int rank = 0;
    for (int q = o0; q < o1; q++) rank += (eids[q] < e);
    int src = decode_src(e, NB * KNN, knn);
    float dx = pos[src * 3] - pos[d * 3];
    float dy = pos[src * 3 + 1] - pos[d * 3 + 1];
    float dz = pos[src * 3 + 2] - pos[d * 3 + 2];
    float d2 = dx * dx + dy * dy + dz * dz;
    float dd = d2 > 0.f ? sqrtf(d2) : 0.f;
    float acc = b2[0];
    #pragma unroll
    for (int k = 0; k < 32; k++) {
        float hh = fmaxf(dd * w1[k] + b1[k], 0.f);
        acc += hh * w2[k];
    }
    srcs[o0 + rank] = src;
    ews[o0 + rank] = fmaxf(acc, 0.f);
}

// pack all 4 layers W^T bf16: BT[layer][n][k]
__global__ void wcvt_all_k(const float* __restrict__ Wl, const float* __restrict__ Wr,
                           ushortT* __restrict__ BT) {
    int i = blockIdx.x * 256 + threadIdx.x;
    if (i >= 4 * 128 * 768) return;
    int layer = i / 98304, rem = i % 98304;
    int k = rem / 768, n = rem % 768;
    const float* W = (n < 384) ? (Wl + (size_t)layer * 128 * 384) : (Wr + (size_t)layer * 128 * 384);
    int nn = (n < 384) ? n : n - 384;
    BT[(size_t)layer * 98304 + (size_t)n * 128 + k] = f2bf(W[k * 384 + nn]);
}

// ---------------- MFMA bf16 GEMM: C[M,768] = A[M,128] @ W  (BT = W^T bf16) ----------------
__global__ __launch_bounds__(256) void gemm_mfma_k(const ushortT* __restrict__ A,
                                                   const ushortT* __restrict__ BT,
                                                   ushortT* __restrict__ C, int M) {
    __shared__ ushortT As[128 * 128];
    __shared__ ushortT Bs[128 * 128];
    int nb = blockIdx.x % 6, mb = blockIdx.x / 6;
    int row0 = mb * 128, col0 = nb * 128;
    int tid = threadIdx.x;
    #pragma unroll
    for (int it = 0; it < 8; it++) {
        int idx = tid + it * 256;          // 16B units
        int row = idx >> 4, seg = idx & 15;
        int byte = (row * 256 + seg * 16) ^ ((row & 7) << 4);
        *(float4*)((char*)As + byte) =
            *(const float4*)((const char*)(A + (size_t)(row0 + row) * 128) + seg * 16);
        *(float4*)((char*)Bs + byte) =
            *(const float4*)((const char*)(BT + (size_t)(col0 + row) * 128) + seg * 16);
    }
    __syncthreads();
    int wave = tid >> 6, lane = tid & 63;
    int wr = wave >> 1, wc = wave & 1;
    f32x4 acc[4][4] = {};
    int lrow = lane & 15;
    int lkb = (lane >> 4) * 16;
    #pragma unroll
    for (int ks = 0; ks < 4; ks++) {
        short8 af[4], bfr[4];
        #pragma unroll
        for (int m = 0; m < 4; m++) {
            int row = wr * 64 + m * 16 + lrow;
            int byte = (row * 256 + ks * 64 + lkb) ^ ((row & 7) << 4);
            af[m] = *(short8*)((char*)As + byte);
        }
        #pragma unroll
        for (int n = 0; n < 4; n++) {
            int col = wc * 64 + n * 16 + lrow;
            int byte = (col * 256 + ks * 64 + lkb) ^ ((col & 7) << 4);
            bfr[n] = *(short8*)((char*)Bs + byte);
        }
        #pragma unroll
        for (int m = 0; m < 4; m++)
            #pragma unroll
            for (int n = 0; n < 4; n++)
                acc[m][n] = __builtin_amdgcn_mfma_f32_16x16x32_bf16(af[m], bfr[n], acc[m][n], 0, 0, 0);
    }
    #pragma unroll
    for (int m = 0; m < 4; m++)
        #pragma unroll
        for (int n = 0; n < 4; n++) {
            int r0 = row0 + wr * 64 + m * 16 + (lane >> 4) * 4;
            int c = col0 + wc * 64 + n * 16 + (lane & 15);
            #pragma unroll
            for (int j = 0; j < 4; j++)
                C[(size_t)(r0 + j) * 768 + c] = f2bf(acc[m][n][j]);
        }
}

// ---------------- fused GAT: persistent grid, half-wave per edge, DPP reduce ----------------
__global__ __launch_bounds__(256) void gat_fused_k(
        const float* __restrict__ hin, const ushortT* __restrict__ xlr,
        const int* __restrict__ off, const int* __restrict__ srcs,
        const float* __restrict__ ews, int NB, int n,
        const float* __restrict__ We, const float* __restrict__ att,
        const float* __restrict__ bias, float* __restrict__ hout) {
    int bpg = n >> 2;
    int nslots = NB >> 2;
    int lane = threadIdx.x & 63;
    int l = lane & 31, half = lane >> 5;
    int wid = threadIdx.x >> 6;
    for (int sb = blockIdx.x; sb < nslots; sb += 2048) {
        int xcd = sb & 7, slot = sb >> 3;
        int gid = xcd + 8 * (slot / bpg);
        int node = gid * n + (slot % bpg) * 4 + wid;
        if (node >= NB) continue;
        f32x2 weP[3][2], atP[3][2], xrP[3][2];
        const ushortT* xrp = xlr + (size_t)node * 768 + 384;
        #pragma unroll
        for (int j = 0; j < 3; j++) {
            float4 wv = *(const float4*)(We + j * 128 + l * 4);
            float4 av = *(const float4*)(att + j * 128 + l * 4);
            uint2 u = *(const uint2*)(xrp + j * 128 + l * 4);
            weP[j][0] = f32x2{wv.x, wv.y}; weP[j][1] = f32x2{wv.z, wv.w};
            atP[j][0] = f32x2{av.x, av.y}; atP[j][1] = f32x2{av.z, av.w};
            xrP[j][0] = f32x2{__uint_as_float(u.x << 16), __uint_as_float(u.x & 0xFFFF0000u)};
            xrP[j][1] = f32x2{__uint_as_float(u.y << 16), __uint_as_float(u.y & 0xFFFF0000u)};
        }
        float d[3] = {0.f, 0.f, 0.f};
        f32x2 acc[3][2] = {};
        int o0 = off[node], o1 = off[node + 1];
        int o = o0 + half;
        int src = 0; float w = 0.f;
        if (o < o1) { src = srcs[o]; w = ews[o]; }
        while (o < o1) {
            int on = o + 2;
            int src_n = 0; float w_n = 0.f;
            if (on < o1) { src_n = srcs[on]; w_n = ews[on]; }
            const ushortT* pl = xlr + (size_t)src * 768;
            float p[3];
            f32x2 xv[3][2];
            #pragma unroll
            for (int j = 0; j < 3; j++) {
                uint2 u = *(const uint2*)(pl + j * 128 + l * 4);
                f32x2 x0 = {__uint_as_float(u.x << 16), __uint_as_float(u.x & 0xFFFF0000u)};
                f32x2 x1 = {__uint_as_float(u.y << 16), __uint_as_float(u.y & 0xFFFF0000u)};
                xv[j][0] = x0; xv[j][1] = x1;
                f32x2 z0 = x0 + (xrP[j][0] + w * weP[j][0]);
                f32x2 z1 = x1 + (xrP[j][1] + w * weP[j][1]);
                z0 = __builtin_elementwise_max(z0, z0 * 0.2f);
                z1 = __builtin_elementwise_max(z1, z1 * 0.2f);
                f32x2 pv = z0 * atP[j][0] + z1 * atP[j][1];
                p[j] = pv.x + pv.y;
            }
            #pragma unroll
            for (int j = 0; j < 3; j++) {
                p[j] = dpp_rowsum(p[j]);
                p[j] += __shfl_xor(p[j], 16);
            }
            #pragma unroll
            for (int j = 0; j < 3; j++) {
                float e = __expf(fminf(p[j], 60.f));
                d[j] += e;
                acc[j][0] += e * xv[j][0];
                acc[j][1] += e * xv[j][1];
            }
            o = on; src = src_n; w = w_n;
        }
        #pragma unroll
        for (int j = 0; j < 3; j++) {
            d[j] += __shfl_xor(d[j], 32);
            #pragma unroll
            for (int pr = 0; pr < 2; pr++) {
                acc[j][pr].x += __shfl_xor(acc[j][pr].x, 32);
                acc[j][pr].y += __shfl_xor(acc[j][pr].y, 32);
            }
        }
        if (half == 0) {
            float4 bv = *(const float4*)(bias + l * 4);
            float4 hv = *(const float4*)(hin + (size_t)node * H + l * 4);
            float i0 = 1.f / d[0], i1 = 1.f / d[1], i2 = 1.f / d[2];
            float av[4] = {acc[0][0].x, acc[0][0].y, acc[0][1].x, acc[0][1].y};
            float bv1[4] = {acc[1][0].x, acc[1][0].y, acc[1][1].x, acc[1][1].y};
            float cv[4] = {acc[2][0].x, acc[2][0].y, acc[2][1].x, acc[2][1].y};
            float bb[4] = {bv.x, bv.y, bv.z, bv.w};
            float hh[4] = {hv.x, hv.y, hv.z, hv.w};
            float ob[4];
            #pragma unroll
            for (int q = 0; q < 4; q++) {
                float g = (av[q] * i0 + bv1[q] * i1 + cv[q] * i2) * (1.f / 3.f) + bb[q];
                float xa = hh[q] + g;
                ob[q] = xa / (1.f + __expf(-xa));
            }
            *(float4*)(hout + (size_t)node * H + l * 4) = make_float4(ob[0], ob[1], ob[2], ob[3]);
        }
    }
}

// ---------------- output head ----------------
__global__ void head_k(const float* __restrict__ cat, const float* __restrict__ W1,
                       const float* __restrict__ b1, const float* __restrict__ W2,
                       const float* __restrict__ b2, float* __restrict__ outp) {
    int b = blockIdx.x, d = threadIdx.x; // 128
    __shared__ float cs[768];
    __shared__ float o1[128];
    for (int i = d; i < 768; i += 128) cs[i] = cat[b * 768 + i];
    __syncthreads();
    float s = b1[d];
    for (int c = 0; c < 768; c++) s += cs[c] * W1[c * 128 + d];
    o1[d] = fmaxf(s, 0.f);
    __syncthreads();
    float s2 = b2[d];
    for (int c = 0; c < 128; c++) s2 += o1[c] * W2[c * 128 + d];
    outp[b * 128 + d] = s2;
}

// ---------------- driver ----------------
extern "C" void kernel_launch(void* const* d_in, const int* in_sizes, int n_in,
                              void* d_out, int out_size, void* d_ws, size_t ws_size,
                              hipStream_t stream) {
    (void)in_sizes; (void)n_in; (void)out_size; (void)ws_size;
    const float* x        = (const float*)d_in[0];
    const float* pos      = (const float*)d_in[1];
    const float* bn_g     = (const float*)d_in[2];
    const float* bn_b     = (const float*)d_in[3];
    const float* conv_Wl  = (const float*)d_in[4];
    const float* conv_Wr  = (const float*)d_in[5];
    const float* conv_We  = (const float*)d_in[6];
    const float* conv_att = (const float*)d_in[7];
    const float* conv_bias= (const float*)d_in[8];
    const float* pool_w   = (const float*)d_in[9];
    const float* gate_w   = (const float*)d_in[10];
    const float* gate_b   = (const float*)d_in[11];
    const float* ro_w     = (const float*)d_in[12];
    const float* ro_b     = (const float*)d_in[13];
    const float* em_w1    = (const float*)d_in[14];
    const float* em_b1    = (const float*)d_in[15];
    const float* em_w2    = (const float*)d_in[16];
    const float* em_b2    = (const float*)d_in[17];
    const float* out_w1   = (const float*)d_in[18];
    const float* out_b1   = (const float*)d_in[19];
    const float* out_w2   = (const float*)d_in[20];
    const float* out_b2   = (const float*)d_in[21];
    float* outp = (float*)d_out;

    const int E1 = BGR * N1C * KNN * 2 + BGR * N1C; // 344064
    char* ws = (char*)d_ws;
    size_t o = 0;
    auto take = [&](size_t bytes) -> char* {
        char* p = ws + o;
        o += (bytes + 255) & ~(size_t)255;
        return p;
    };
    ushortT* xlrb = (ushortT*)take((size_t)16384 * 768 * 2);
    ushortT* hbf  = (ushortT*)take((size_t)16384 * 128 * 2);
    ushortT* wbt4 = (ushortT*)take((size_t)4 * 768 * 128 * 2);
    float* h0     = (float*)take((size_t)32768 * 128 * 4);
    float* h1a    = (float*)take((size_t)16384 * 128 * 4);
    float* h1b    = (float*)take((size_t)16384 * 128 * 4);
    float* h2a    = (float*)take((size_t)8192 * 128 * 4);
    float* h2b    = (float*)take((size_t)8192 * 128 * 4);
    float* ews    = (float*)take((size_t)E1 * 4);
    float* pos1   = (float*)take((size_t)16384 * 3 * 4);
    float* pos2   = (float*)take((size_t)8192 * 3 * 4);
    float* plog   = (float*)take((size_t)32768 * 4);
    float* vals   = (float*)take((size_t)16384 * 4);
    float* apart  = (float*)take((size_t)16 * 32 * 128 * 4);
    float* catb   = (float*)take((size_t)12288 * 4);
    float* stats  = (float*)take((size_t)256 * 4);
    float* parts  = (float*)take((size_t)CS_BLOCKS * 256 * 4);
    int* knnb     = (int*)take((size_t)163840 * 4);
    int* permb    = (int*)take((size_t)16384 * 4);
    int* degb     = (int*)take((size_t)16385 * 4);
    int* offb     = (int*)take((size_t)16385 * 4);
    int* curb     = (int*)take((size_t)16384 * 4);
    int* eidsb    = (int*)take((size_t)E1 * 4);
    int* dstsb    = (int*)take((size_t)E1 * 4);
    int* srcsb    = (int*)take((size_t)E1 * 4);

    auto run_bn = [&](const float* in, float* out2, ushortT* bf, int rows, int layer,
                      const float* gw, const float* gbp) {
        colstats_k<<<CS_BLOCKS, 256, 0, stream>>>(in, rows, parts);
        colreduce_k<<<1, 256, 0, stream>>>(parts, stats);
        bn_apply_k<<<(rows * 128) / 256, 256, 0, stream>>>(in, out2, bf, stats,
                                                           bn_g + layer * H, bn_b + layer * H,
                                                           gw, gbp, plog, rows);
    };
    auto run_pool = [&](const float* hsrc, const float* possrc, float* hdst, float* posdst,
                        int n, int keep, const float* gw, const float* gbp) {
        pool_rank_k<<<BGR * (n / 64), 256, 0, stream>>>(plog, n, keep, permb, vals);
        pool_gather_k<<<(BGR * keep * 128) / 256, 256, 0, stream>>>(hsrc, possrc, permb, vals,
                                                                    hdst, hbf, posdst,
                                                                    gw, gbp, plog, BGR * keep);
    };
    auto run_readout = [&](const float* hsrc, int n, int g, int catoff) {
        int chunks = n / 64;
        att_partial_k<<<BGR * chunks, 256, 0, stream>>>(hsrc, plog, n, apart);
        ro_gemm_k<<<BGR, 256, 0, stream>>>(apart, chunks, ro_w + (size_t)g * H * 256, ro_b + g * 256, catb, catoff);
    };
    auto build_graph = [&](const float* posb, int n, int st) {
        int NB = BGR * n, E = NB * KNN * 2 + NB;
        hipMemsetAsync(degb, 0, (size_t)NB * 4, stream);
        knn_k<<<NB / 4, 256, 0, stream>>>(posb, n, knnb, degb);
        scan_k<<<1, 1024, 0, stream>>>(degb, offb, curb, NB);
        fill_eids_k<<<E / 256, 256, 0, stream>>>(knnb, NB, E, curb, eidsb, dstsb);
        rank_gather_k<<<E / 256, 256, 0, stream>>>(eidsb, dstsb, offb, knnb, posb, NB, E,
                                                   em_w1 + st * 32, em_b1 + st * 32,
                                                   em_w2 + st * 32, em_b2 + st, srcsb, ews);
    };
    auto run_gat = [&](const float* hin, float* hout, int NB, int n, int layer) {
        gemm_mfma_k<<<(NB / 128) * 6, 256, 0, stream>>>(hbf, wbt4 + (size_t)layer * 98304, xlrb, NB);
        int nslots = NB / 4;
        int grid = nslots < 2048 ? nslots : 2048;
        gat_fused_k<<<grid, 256, 0, stream>>>(hin, xlrb, offb, srcsb, ews, NB, n,
                                              conv_We + layer * 384, conv_att + layer * 384,
                                              conv_bias + layer * H, hout);
    };

    wcvt_all_k<<<1536, 256, 0, stream>>>(conv_Wl, conv_Wr, wbt4);
    run_bn(x, h0, nullptr, BGR * N0C, 0, pool_w, nullptr);
    run_pool(h0, pos, h1a, pos1, N0C, N1C, gate_w, gate_b);
    run_readout(h1a, N1C, 0, 512);
    build_graph(pos1, N1C, 0);
    run_gat(h1a, h1b, BGR * N1C, N1C, 0);
    run_bn(h1b, h1a, hbf, BGR * N1C, 1, nullptr, nullptr);
    run_gat(h1a, h1b, BGR * N1C, N1C, 1);
    run_bn(h1b, h1a, nullptr, BGR * N1C, 2, pool_w + H, nullptr);
    run_pool(h1a, pos1, h2a, pos2, N1C, N2C, gate_w + H, gate_b + 1);
    run_readout(h2a, N2C, 1, 256);
    build_graph(pos2, N2C, 1);
    run_gat(h2a, h2b, BGR * N2C, N2C, 2);
    run_bn(h2b, h2a, hbf, BGR * N2C, 3, nullptr, nullptr);
    run_gat(h2a, h2b, BGR * N2C, N2C, 3);
    run_bn(h2b, h2a, nullptr, BGR * N2C, 4, gate_w + 2 * H, gate_b + 2);
    run_readout(h2a, N2C, 2, 0);
    head_k<<<BGR, 128, 0, stream>>>(catb, out_w1, out_b1, out_w2, out_b2, outp);
}